// Round 8
// baseline (488.053 us; speedup 1.0000x reference)
//
#include <hip/hip_runtime.h>

#define NR 128        // dst nodes per bucket
#define PART_CH 8192  // edges per hist/partition block
typedef unsigned short ushortT;
typedef __attribute__((ext_vector_type(8))) short short8;
typedef __attribute__((ext_vector_type(4))) float float4v;
typedef __attribute__((ext_vector_type(2))) float float2v;

__device__ __forceinline__ unsigned short f32_to_bf16_rne(float f) {
    unsigned u = __float_as_uint(f);
    unsigned r = (u + 0x7fffu + ((u >> 16) & 1u)) >> 16;
    return (unsigned short)r;
}

__device__ __forceinline__ unsigned char f32_to_fp8(float f) {
    return (unsigned char)(__builtin_amdgcn_cvt_pk_fp8_f32(f, f, 0, false) & 0xff);
}

__device__ __forceinline__ void accum8(float* acc, uint4 v) {
    unsigned u[4] = {v.x, v.y, v.z, v.w};
#pragma unroll
    for (int q = 0; q < 4; q++) {
        acc[2 * q]     += __uint_as_float(u[q] << 16);
        acc[2 * q + 1] += __uint_as_float(u[q] & 0xffff0000u);
    }
}

// 16 fp8 values in a uint4 -> acc[16]
__device__ __forceinline__ void accum16_fp8(float* acc, uint4 v) {
    unsigned u[4] = {v.x, v.y, v.z, v.w};
#pragma unroll
    for (int q = 0; q < 4; q++) {
        float2v lo = __builtin_amdgcn_cvt_pk_f32_fp8(u[q], false);
        float2v hi = __builtin_amdgcn_cvt_pk_f32_fp8(u[q], true);
        acc[4 * q + 0] += lo.x;
        acc[4 * q + 1] += lo.y;
        acc[4 * q + 2] += hi.x;
        acc[4 * q + 3] += hi.y;
    }
}

// ---------------- CSR build: radix-style with precomputed bases ----------------

__launch_bounds__(256)
__global__ void hist_pass(const int* __restrict__ dst, int* __restrict__ hist_blk, int E, int NB) {
    __shared__ int h[1024];
    int t = threadIdx.x;
    for (int j = t; j < 1024; j += 256) h[j] = 0;
    __syncthreads();
    int e0 = blockIdx.x * PART_CH;
    int e1 = min(e0 + PART_CH, E);
    for (int base = e0; base < e1; base += 2048) {
        int idx = base + t;
        int d[8];
        int cnt = 0;
#pragma unroll
        for (int u = 0; u < 8; u++) {
            int e = idx + u * 256;
            if (e < e1) d[cnt++] = dst[e];
        }
        for (int u = 0; u < cnt; u++) atomicAdd(&h[d[u] >> 7], 1);
    }
    __syncthreads();
    int* row = hist_blk + (size_t)blockIdx.x * NB;
    for (int j = t; j < NB; j += 256) row[j] = h[j];
}

// single block, 1024 threads: bucket totals -> exclusive scan -> bstart + per-block bases
__launch_bounds__(1024)
__global__ void pbase_scan(const int* __restrict__ hist_blk, int* __restrict__ bstart,
                           int* __restrict__ pbase, int NB, int NBLK, int E) {
    __shared__ int sh[1024];
    int t = threadIdx.x;
    int tot = 0;
    if (t < NB)
        for (int b = 0; b < NBLK; b++) tot += hist_blk[(size_t)b * NB + t];
    sh[t] = tot;
    __syncthreads();
    for (int off = 1; off < 1024; off <<= 1) {
        int add = (t >= off) ? sh[t - off] : 0;
        __syncthreads();
        sh[t] += add;
        __syncthreads();
    }
    int excl = sh[t] - tot;
    if (t < NB) {
        bstart[t] = excl;
        int run = excl;
        for (int b = 0; b < NBLK; b++) {
            size_t idx = (size_t)b * NB + t;
            pbase[idx] = run;
            run += hist_blk[idx];
        }
    }
    if (t == 0) bstart[NB] = E;
}

// single pass: scatter packed records using precomputed LDS cursors (no global atomics)
// packed record = src | (dst&127)<<17  (src < 2^17)
__launch_bounds__(256)
__global__ void partition_edges(const int* __restrict__ src, const int* __restrict__ dst,
                                const int* __restrict__ pbase, unsigned* __restrict__ packed,
                                int E, int NB) {
    __shared__ int cur[1024];
    int t = threadIdx.x, b = blockIdx.x;
    const int* prow = pbase + (size_t)b * NB;
    for (int j = t; j < NB; j += 256) cur[j] = prow[j];
    __syncthreads();
    int e0 = b * PART_CH;
    int e1 = min(e0 + PART_CH, E);
    for (int base = e0; base < e1; base += 2048) {
        int idx = base + t;
        int d[8], s[8];
        int cnt = 0;
#pragma unroll
        for (int u = 0; u < 8; u++) {
            int e = idx + u * 256;
            if (e < e1) { d[cnt] = dst[e]; s[cnt] = src[e]; cnt++; }
        }
        for (int u = 0; u < cnt; u++) {
            int dd = d[u];
            int pos = atomicAdd(&cur[dd >> 7], 1);
            packed[pos] = (unsigned)s[u] | ((unsigned)(dd & (NR - 1)) << 17);
        }
    }
}

__launch_bounds__(256)
__global__ void bucket_sort(const unsigned* __restrict__ packed, const int* __restrict__ bstart,
                            int* __restrict__ row_start, int* __restrict__ srcs, int N) {
    __shared__ int cnt[NR];
    __shared__ int sc[NR];
    __shared__ int cur[NR];
    int b = blockIdx.x, t = threadIdx.x;
    int nb0 = b * NR;
    int nnode = min(NR, N - nb0);
    int lo = bstart[b], hi = bstart[b + 1];
    if (t < NR) cnt[t] = 0;
    __syncthreads();
    for (int base = lo; base < hi; base += 2048) {
        int idx = base + t;
        unsigned pk[8];
        int c = 0;
#pragma unroll
        for (int u = 0; u < 8; u++) {
            int e = idx + u * 256;
            if (e < hi) pk[c++] = packed[e];
        }
        for (int u = 0; u < c; u++) atomicAdd(&cnt[pk[u] >> 17], 1);
    }
    __syncthreads();
    if (t < NR) sc[t] = cnt[t];
    __syncthreads();
    for (int off = 1; off < NR; off <<= 1) {
        int add = (t >= off && t < NR) ? sc[t - off] : 0;
        __syncthreads();
        if (t < NR) sc[t] += add;
        __syncthreads();
    }
    if (t < nnode) {
        int s = lo + sc[t] - cnt[t];
        row_start[nb0 + t] = s;
        cur[t] = s;
    }
    if (t == 0 && nb0 + nnode == N) row_start[N] = hi;
    __syncthreads();
    for (int base = lo; base < hi; base += 2048) {
        int idx = base + t;
        unsigned pk[8];
        int c = 0;
#pragma unroll
        for (int u = 0; u < 8; u++) {
            int e = idx + u * 256;
            if (e < hi) pk[c++] = packed[e];
        }
        for (int u = 0; u < c; u++) {
            int pos = atomicAdd(&cur[pk[u] >> 17], 1);
            srcs[pos] = (int)(pk[u] & 0x1FFFFu);
        }
    }
}

// ---------------- f32 -> bf16 ----------------

__global__ void to_bf16_vec(const float* __restrict__ in, ushortT* __restrict__ out, int n4) {
    int t = blockIdx.x * 256 + threadIdx.x;
    if (t < n4) {
        float4 v = ((const float4*)in)[t];
        ushort4 o;
        o.x = f32_to_bf16_rne(v.x);
        o.y = f32_to_bf16_rne(v.y);
        o.z = f32_to_bf16_rne(v.z);
        o.w = f32_to_bf16_rne(v.w);
        ((ushort4*)out)[t] = o;
    }
}

// ---------------- all weight preps, one kernel ----------------
// Wt layout: Wt[col][(k + 8*col) % KT] = bf16(Wcat[k][col])

__global__ void prep_all(const float* __restrict__ Wl0, const float* __restrict__ Wr0,
                         const float* __restrict__ Wl1, const float* __restrict__ Wr1,
                         const float* __restrict__ Wl2, const float* __restrict__ Wr2,
                         const float* __restrict__ Wa2,
                         ushortT* __restrict__ Wt0, ushortT* __restrict__ Wt1,
                         ushortT* __restrict__ Wt2, ushortT* __restrict__ Wa2t) {
    int tid = blockIdx.x * 256 + threadIdx.x;
    if (tid < 8192) {  // Wt0: KH=32, KT=64
        int col = tid >> 6, k = tid & 63;
        float v = (k < 32) ? Wl0[k * 128 + col] : Wr0[(k - 32) * 128 + col];
        Wt0[col * 64 + ((k + 8 * col) & 63)] = f32_to_bf16_rne(v);
    } else if (tid < 8192 + 32768) {  // Wt1: KT=256
        int j = tid - 8192;
        int col = j >> 8, k = j & 255;
        float v = (k < 128) ? Wl1[k * 128 + col] : Wr1[(k - 128) * 128 + col];
        Wt1[col * 256 + ((k + 8 * col) & 255)] = f32_to_bf16_rne(v);
    } else if (tid < 8192 + 65536) {  // Wt2: KT=256
        int j = tid - 8192 - 32768;
        int col = j >> 8, k = j & 255;
        float v = (k < 128) ? Wl2[k * 128 + col] : Wr2[(k - 128) * 128 + col];
        Wt2[col * 256 + ((k + 8 * col) & 255)] = f32_to_bf16_rne(v);
    } else if (tid < 8192 + 65536 + 16384) {  // Wa2t: KT=128
        int j = tid - 8192 - 65536;
        int col = j >> 7, k = j & 127;
        Wa2t[col * 128 + ((k + 8 * col) & 127)] = f32_to_bf16_rne(Wa2[k * 128 + col]);
    }
}

// ---------------- aggregation: bf16 input (layer 0, 32 feats) ----------------

template <int CPN>
__launch_bounds__(256)
__global__ void aggregate_mean_bf16(const uint4* __restrict__ hin, ushortT* __restrict__ out,
                                    const int* __restrict__ srcs, const int* __restrict__ rs, int n) {
    constexpr int TPN = CPN / 2;
    int tid = blockIdx.x * 256 + threadIdx.x;
    if (tid >= n * TPN) return;
    int i = tid / TPN;
    int c = tid & (TPN - 1);
    int lo = rs[i], hi = rs[i + 1];
    float acc0[8], acc1[8];
#pragma unroll
    for (int q = 0; q < 8; q++) { acc0[q] = 0.f; acc1[q] = 0.f; }
    int e = lo;
    for (; e + 8 <= hi; e += 8) {
        int s[8];
#pragma unroll
        for (int u = 0; u < 8; u++) s[u] = srcs[e + u];
        uint4 va[8], vb[8];
#pragma unroll
        for (int u = 0; u < 8; u++) {
            va[u] = hin[(size_t)s[u] * CPN + c];
            vb[u] = hin[(size_t)s[u] * CPN + c + TPN];
        }
#pragma unroll
        for (int u = 0; u < 8; u++) { accum8(acc0, va[u]); accum8(acc1, vb[u]); }
    }
    for (; e < hi; ++e) {
        int s = srcs[e];
        accum8(acc0, hin[(size_t)s * CPN + c]);
        accum8(acc1, hin[(size_t)s * CPN + c + TPN]);
    }
    float inv = 1.0f / (float)max(hi - lo, 1);
    uint4 o0, o1;
    o0.x = (unsigned)f32_to_bf16_rne(acc0[0] * inv) | ((unsigned)f32_to_bf16_rne(acc0[1] * inv) << 16);
    o0.y = (unsigned)f32_to_bf16_rne(acc0[2] * inv) | ((unsigned)f32_to_bf16_rne(acc0[3] * inv) << 16);
    o0.z = (unsigned)f32_to_bf16_rne(acc0[4] * inv) | ((unsigned)f32_to_bf16_rne(acc0[5] * inv) << 16);
    o0.w = (unsigned)f32_to_bf16_rne(acc0[6] * inv) | ((unsigned)f32_to_bf16_rne(acc0[7] * inv) << 16);
    o1.x = (unsigned)f32_to_bf16_rne(acc1[0] * inv) | ((unsigned)f32_to_bf16_rne(acc1[1] * inv) << 16);
    o1.y = (unsigned)f32_to_bf16_rne(acc1[2] * inv) | ((unsigned)f32_to_bf16_rne(acc1[3] * inv) << 16);
    o1.z = (unsigned)f32_to_bf16_rne(acc1[4] * inv) | ((unsigned)f32_to_bf16_rne(acc1[5] * inv) << 16);
    o1.w = (unsigned)f32_to_bf16_rne(acc1[6] * inv) | ((unsigned)f32_to_bf16_rne(acc1[7] * inv) << 16);
    ((uint4*)out)[(size_t)i * CPN + c] = o0;
    ((uint4*)out)[(size_t)i * CPN + c + TPN] = o1;
}

// ---------------- aggregation: fp8 input (layers 1/2, 128 feats) ----------------
// 4 threads/node; each owns fp8 chunks c and c+4 (16 feats each) -> 16 loads in flight.

__launch_bounds__(256)
__global__ void aggregate_mean_fp8(const uint4* __restrict__ hin, ushortT* __restrict__ out,
                                   const int* __restrict__ srcs, const int* __restrict__ rs, int n) {
    int tid = blockIdx.x * 256 + threadIdx.x;
    if (tid >= n * 4) return;
    int i = tid >> 2;
    int c = tid & 3;
    int lo = rs[i], hi = rs[i + 1];
    float acc0[16], acc1[16];
#pragma unroll
    for (int q = 0; q < 16; q++) { acc0[q] = 0.f; acc1[q] = 0.f; }
    int e = lo;
    for (; e + 8 <= hi; e += 8) {
        int s[8];
#pragma unroll
        for (int u = 0; u < 8; u++) s[u] = srcs[e + u];
        uint4 va[8], vb[8];
#pragma unroll
        for (int u = 0; u < 8; u++) {
            va[u] = hin[(size_t)s[u] * 8 + c];
            vb[u] = hin[(size_t)s[u] * 8 + c + 4];
        }
#pragma unroll
        for (int u = 0; u < 8; u++) { accum16_fp8(acc0, va[u]); accum16_fp8(acc1, vb[u]); }
    }
    for (; e < hi; ++e) {
        int s = srcs[e];
        accum16_fp8(acc0, hin[(size_t)s * 8 + c]);
        accum16_fp8(acc1, hin[(size_t)s * 8 + c + 4]);
    }
    float inv = 1.0f / (float)max(hi - lo, 1);
    uint4 o;
#pragma unroll
    for (int half = 0; half < 2; ++half) {
        float* a = half ? acc1 : acc0;
        int cb = half ? (2 * c + 8) : (2 * c);
        o.x = (unsigned)f32_to_bf16_rne(a[0] * inv)  | ((unsigned)f32_to_bf16_rne(a[1] * inv) << 16);
        o.y = (unsigned)f32_to_bf16_rne(a[2] * inv)  | ((unsigned)f32_to_bf16_rne(a[3] * inv) << 16);
        o.z = (unsigned)f32_to_bf16_rne(a[4] * inv)  | ((unsigned)f32_to_bf16_rne(a[5] * inv) << 16);
        o.w = (unsigned)f32_to_bf16_rne(a[6] * inv)  | ((unsigned)f32_to_bf16_rne(a[7] * inv) << 16);
        ((uint4*)out)[(size_t)i * 16 + cb] = o;
        o.x = (unsigned)f32_to_bf16_rne(a[8] * inv)  | ((unsigned)f32_to_bf16_rne(a[9] * inv) << 16);
        o.y = (unsigned)f32_to_bf16_rne(a[10] * inv) | ((unsigned)f32_to_bf16_rne(a[11] * inv) << 16);
        o.z = (unsigned)f32_to_bf16_rne(a[12] * inv) | ((unsigned)f32_to_bf16_rne(a[13] * inv) << 16);
        o.w = (unsigned)f32_to_bf16_rne(a[14] * inv) | ((unsigned)f32_to_bf16_rne(a[15] * inv) << 16);
        ((uint4*)out)[(size_t)i * 16 + cb + 1] = o;
    }
}

// ---------------- MFMA GEMM: out = relu([Am | Ah] @ [Wl;Wr] + bias) --------------------

template <int KH, bool OUT_BF16, bool OUT_FP8>
__launch_bounds__(256, 2)
__global__ void gemm_mfma(const ushortT* __restrict__ Am, const ushortT* __restrict__ Ah,
                          const ushortT* __restrict__ Wt, const float* __restrict__ bias,
                          float* __restrict__ outf, ushortT* __restrict__ outbf,
                          unsigned char* __restrict__ outf8, int n) {
    constexpr int KT = 2 * KH;
    __shared__ ushortT sW[128 * KT];
    int t = threadIdx.x;
    constexpr int TOT16 = 128 * KT * 2 / 16;
    {
        const uint4* Wg = (const uint4*)Wt;
        uint4* Ws = (uint4*)sW;
        for (int j = t; j < TOT16; j += 256) Ws[j] = Wg[j];
    }
    __syncthreads();
    int wv = t >> 6, lane = t & 63;
    int q = lane >> 4, cid = lane & 15;
    int rbase = blockIdx.x * 128 + wv * 32;
    int r0 = rbase + cid, r1 = r0 + 16;
    int r0c = min(r0, n - 1), r1c = min(r1, n - 1);
    float4v acc[2][8];
#pragma unroll
    for (int i = 0; i < 2; i++)
#pragma unroll
        for (int j = 0; j < 8; j++) acc[i][j] = (float4v){0.f, 0.f, 0.f, 0.f};
    int swz = q * 8 + 8 * cid;
#pragma unroll
    for (int ks = 0; ks < KT / 32; ++ks) {
        int kk = ks * 32;
        const ushortT* abase = (kk < KH) ? Am : Ah;
        int kc = (kk < KH) ? kk : kk - KH;
        short8 a0 = *(const short8*)(abase + (size_t)r0c * KH + kc + q * 8);
        short8 a1 = *(const short8*)(abase + (size_t)r1c * KH + kc + q * 8);
#pragma unroll
        for (int j = 0; j < 8; ++j) {
            int col = j * 16 + cid;
            int p = (kk + swz + j * 128) & (KT - 1);
            short8 b = *(const short8*)(sW + col * KT + p);
            acc[0][j] = __builtin_amdgcn_mfma_f32_16x16x32_bf16(a0, b, acc[0][j], 0, 0, 0);
            acc[1][j] = __builtin_amdgcn_mfma_f32_16x16x32_bf16(a1, b, acc[1][j], 0, 0, 0);
        }
    }
    float bo[8];
#pragma unroll
    for (int j = 0; j < 8; ++j) bo[j] = bias[j * 16 + cid];
#pragma unroll
    for (int i = 0; i < 2; ++i) {
#pragma unroll
        for (int rr = 0; rr < 4; ++rr) {
            int row = rbase + i * 16 + q * 4 + rr;
            if (row < n) {
#pragma unroll
                for (int j = 0; j < 8; ++j) {
                    int col = j * 16 + cid;
                    float v = fmaxf(acc[i][j][rr] + bo[j], 0.f);
                    if (OUT_BF16) outbf[(size_t)row * 128 + col] = f32_to_bf16_rne(v);
                    if (OUT_FP8)  outf8[(size_t)row * 128 + col] = f32_to_fp8(v);
                    if (!OUT_BF16 && !OUT_FP8) outf[(size_t)row * 128 + col] = v;
                }
            }
        }
    }
}

// ---- layer-2 variant: h3 never materialized; epilogue computes d1/d3 -> fin[:,0],fin[:,2]

template <int KH>
__launch_bounds__(256, 2)
__global__ void gemm_mfma_fin(const ushortT* __restrict__ Am, const ushortT* __restrict__ Ah,
                              const ushortT* __restrict__ Wt, const float* __restrict__ bias,
                              const float* __restrict__ Wfc, const float* __restrict__ bfc,
                              float* __restrict__ fin, int n) {
    constexpr int KT = 2 * KH;
    __shared__ ushortT sW[128 * KT];
    int t = threadIdx.x;
    constexpr int TOT16 = 128 * KT * 2 / 16;
    {
        const uint4* Wg = (const uint4*)Wt;
        uint4* Ws = (uint4*)sW;
        for (int j = t; j < TOT16; j += 256) Ws[j] = Wg[j];
    }
    __syncthreads();
    int wv = t >> 6, lane = t & 63;
    int q = lane >> 4, cid = lane & 15;
    int rbase = blockIdx.x * 128 + wv * 32;
    int r0 = rbase + cid, r1 = r0 + 16;
    int r0c = min(r0, n - 1), r1c = min(r1, n - 1);
    float4v acc[2][8];
#pragma unroll
    for (int i = 0; i < 2; i++)
#pragma unroll
        for (int j = 0; j < 8; j++) acc[i][j] = (float4v){0.f, 0.f, 0.f, 0.f};
    int swz = q * 8 + 8 * cid;
#pragma unroll
    for (int ks = 0; ks < KT / 32; ++ks) {
        int kk = ks * 32;
        const ushortT* abase = (kk < KH) ? Am : Ah;
        int kc = (kk < KH) ? kk : kk - KH;
        short8 a0 = *(const short8*)(abase + (size_t)r0c * KH + kc + q * 8);
        short8 a1 = *(const short8*)(abase + (size_t)r1c * KH + kc + q * 8);
#pragma unroll
        for (int j = 0; j < 8; ++j) {
            int col = j * 16 + cid;
            int p = (kk + swz + j * 128) & (KT - 1);
            short8 b = *(const short8*)(sW + col * KT + p);
            acc[0][j] = __builtin_amdgcn_mfma_f32_16x16x32_bf16(a0, b, acc[0][j], 0, 0, 0);
            acc[1][j] = __builtin_amdgcn_mfma_f32_16x16x32_bf16(a1, b, acc[1][j], 0, 0, 0);
        }
    }
    float bo[8], w1[8], w3[8];
#pragma unroll
    for (int j = 0; j < 8; ++j) {
        int col = j * 16 + cid;
        bo[j] = bias[col];
        w1[j] = Wfc[col * 3 + 0];
        w3[j] = Wfc[col * 3 + 2];
    }
    float bfc0 = bfc[0], bfc2 = bfc[2];
#pragma unroll
    for (int i = 0; i < 2; ++i) {
#pragma unroll
        for (int rr = 0; rr < 4; ++rr) {
            float p1 = 0.f, p3 = 0.f;
#pragma unroll
            for (int j = 0; j < 8; ++j) {
                float v = fmaxf(acc[i][j][rr] + bo[j], 0.f);
                p1 += v * w1[j];
                p3 += v * w3[j];
            }
            p1 += __shfl_xor(p1, 1, 64); p3 += __shfl_xor(p3, 1, 64);
            p1 += __shfl_xor(p1, 2, 64); p3 += __shfl_xor(p3, 2, 64);
            p1 += __shfl_xor(p1, 4, 64); p3 += __shfl_xor(p3, 4, 64);
            p1 += __shfl_xor(p1, 8, 64); p3 += __shfl_xor(p3, 8, 64);
            int row = rbase + i * 16 + q * 4 + rr;
            if (cid == 0 && row < n) {
                fin[(size_t)row * 3 + 0] = p1 + bfc0;
                fin[(size_t)row * 3 + 2] = p3 + bfc2;
            }
        }
    }
}

// ---------------- head: a1 built in registers + a2 MFMA + Wao reduce -> fin[:,1] -------

__launch_bounds__(256, 4)
__global__ void head_mfma(const ushortT* __restrict__ Wa2t, const float* __restrict__ Wa1,
                          const float* __restrict__ ba1, const float* __restrict__ ba2,
                          const float* __restrict__ Wao, const float* __restrict__ bao,
                          float* __restrict__ fin, int n) {
    __shared__ ushortT sW[128 * 128];   // 32 KB
    __shared__ float sD1[128], sD3[128];
    __shared__ float sWa1a[128], sWa1b[128], sBa1[128];
    int t = threadIdx.x;
    {
        const uint4* Wg = (const uint4*)Wa2t;
        uint4* Ws = (uint4*)sW;
        for (int j = t; j < 2048; j += 256) Ws[j] = Wg[j];
    }
    int rbase = blockIdx.x * 128;
    if (t < 128) {
        sWa1a[t] = Wa1[t];
        sWa1b[t] = Wa1[128 + t];
        sBa1[t] = ba1[t];
        int row = min(rbase + t, n - 1);
        sD1[t] = fin[(size_t)row * 3 + 0];
        sD3[t] = fin[(size_t)row * 3 + 2];
    }
    __syncthreads();
    int wv = t >> 6, lane = t & 63;
    int q = lane >> 4, cid = lane & 15;
    int rl0 = wv * 32 + cid, rl1 = rl0 + 16;
    float d1a = sD1[rl0], d3a = sD3[rl0];
    float d1b = sD1[rl1], d3b = sD3[rl1];
    float4v acc[2][8];
#pragma unroll
    for (int i = 0; i < 2; i++)
#pragma unroll
        for (int j = 0; j < 8; j++) acc[i][j] = (float4v){0.f, 0.f, 0.f, 0.f};
    int swz = q * 8 + 8 * cid;
#pragma unroll
    for (int ks = 0; ks < 4; ++ks) {
        int k0 = ks * 32 + q * 8;
        short8 a0, a1;
#pragma unroll
        for (int j = 0; j < 8; ++j) {
            int k = k0 + j;
            float w0 = sWa1a[k], w1 = sWa1b[k], bb = sBa1[k];
            float v0 = fmaxf(fmaf(d1a, w0, fmaf(d3a, w1, bb)), 0.f);
            float v1 = fmaxf(fmaf(d1b, w0, fmaf(d3b, w1, bb)), 0.f);
            a0[j] = (short)f32_to_bf16_rne(v0);
            a1[j] = (short)f32_to_bf16_rne(v1);
        }
        int p = (ks * 32 + swz) & 127;
#pragma unroll
        for (int j = 0; j < 8; ++j) {
            short8 b = *(const short8*)(sW + (j * 16 + cid) * 128 + p);
            acc[0][j] = __builtin_amdgcn_mfma_f32_16x16x32_bf16(a0, b, acc[0][j], 0, 0, 0);
            acc[1][j] = __builtin_amdgcn_mfma_f32_16x16x32_bf16(a1, b, acc[1][j], 0, 0, 0);
        }
    }
    float b2[8], wo[8];
#pragma unroll
    for (int j = 0; j < 8; ++j) {
        int col = j * 16 + cid;
        b2[j] = ba2[col];
        wo[j] = Wao[col];
    }
    float bao0 = bao[0];
#pragma unroll
    for (int i = 0; i < 2; ++i) {
#pragma unroll
        for (int rr = 0; rr < 4; ++rr) {
            float s = 0.f;
#pragma unroll
            for (int j = 0; j < 8; ++j) s += fmaxf(acc[i][j][rr] + b2[j], 0.f) * wo[j];
            s += __shfl_xor(s, 1, 64);
            s += __shfl_xor(s, 2, 64);
            s += __shfl_xor(s, 4, 64);
            s += __shfl_xor(s, 8, 64);
            int row = rbase + wv * 32 + i * 16 + q * 4 + rr;
            if (cid == 0 && row < n) fin[(size_t)row * 3 + 1] = s + bao0;
        }
    }
}

// ---------------- per-graph mean pool ----------------

__global__ void pool_kernel(const float* __restrict__ fin, const int* __restrict__ batch,
                            float* __restrict__ out, int n) {
    int g = blockIdx.x, t = threadIdx.x;
    int lo = 0, hi = n;
    while (lo < hi) { int mid = (lo + hi) >> 1; if (batch[mid] < g) lo = mid + 1; else hi = mid; }
    int start = lo;
    lo = 0; hi = n;
    while (lo < hi) { int mid = (lo + hi) >> 1; if (batch[mid] < g + 1) lo = mid + 1; else hi = mid; }
    int end = lo;
    float s0 = 0.f, s1 = 0.f, s2 = 0.f;
    for (int i = start + t; i < end; i += 256) {
        s0 += fin[(size_t)i * 3 + 0];
        s1 += fin[(size_t)i * 3 + 1];
        s2 += fin[(size_t)i * 3 + 2];
    }
    __shared__ float r0[256], r1[256], r2[256];
    r0[t] = s0; r1[t] = s1; r2[t] = s2;
    __syncthreads();
    for (int off = 128; off > 0; off >>= 1) {
        if (t < off) { r0[t] += r0[t + off]; r1[t] += r1[t + off]; r2[t] += r2[t + off]; }
        __syncthreads();
    }
    if (t == 0) {
        float c = (float)max(end - start, 1);
        out[g * 3 + 0] = r0[0] / c;
        out[g * 3 + 1] = r1[0] / c;
        out[g * 3 + 2] = r2[0] / c;
    }
}

// ---------------- launch ----------------

extern "C" void kernel_launch(void* const* d_in, const int* in_sizes, int n_in,
                              void* d_out, int out_size, void* d_ws, size_t ws_size,
                              hipStream_t stream) {
    const float* x    = (const float*)d_in[0];
    const int*   ei   = (const int*)d_in[1];
    const int*   batch= (const int*)d_in[2];
    const float* Wl0  = (const float*)d_in[3];
    const float* bl0  = (const float*)d_in[4];
    const float* Wr0  = (const float*)d_in[5];
    const float* Wl1  = (const float*)d_in[6];
    const float* bl1  = (const float*)d_in[7];
    const float* Wr1  = (const float*)d_in[8];
    const float* Wl2  = (const float*)d_in[9];
    const float* bl2  = (const float*)d_in[10];
    const float* Wr2  = (const float*)d_in[11];
    const float* Wfc  = (const float*)d_in[12];
    const float* bfc  = (const float*)d_in[13];
    const float* Wa1  = (const float*)d_in[14];
    const float* ba1  = (const float*)d_in[15];
    const float* Wa2  = (const float*)d_in[16];
    const float* ba2  = (const float*)d_in[17];
    const float* Wao  = (const float*)d_in[18];
    const float* bao  = (const float*)d_in[19];

    const int N = in_sizes[0] / 32;
    const int E = in_sizes[1] / 2;
    const int G = out_size / 3;
    const int* src = ei;
    const int* dst = ei + E;
    float* out = (float*)d_out;
    const int NB = (N + NR - 1) / NR;
    const int NBLK = (E + PART_CH - 1) / PART_CH;

    char* p = (char*)d_ws;
    auto carve = [&](size_t bytes) {
        void* r = (void*)p;
        p += (bytes + 255) & ~(size_t)255;
        return r;
    };
    int*           hist_blk = (int*)carve((size_t)NBLK * NB * 4);
    int*           pbase    = (int*)carve((size_t)NBLK * NB * 4);
    int*           bstart   = (int*)carve((size_t)(NB + 1) * 4);
    int*           row_start= (int*)carve((size_t)(N + 1) * 4);
    unsigned*      packed   = (unsigned*)carve((size_t)E * 4);
    int*           srcs     = (int*)carve((size_t)E * 4);
    ushortT*       aggbf    = (ushortT*)carve((size_t)N * 128 * 2);
    ushortT*       xbf      = (ushortT*)carve((size_t)N * 32 * 2);
    ushortT*       hbf0     = (ushortT*)carve((size_t)N * 128 * 2);
    ushortT*       hbf1     = (ushortT*)carve((size_t)N * 128 * 2);
    unsigned char* hf8_0    = (unsigned char*)carve((size_t)N * 128);
    unsigned char* hf8_1    = (unsigned char*)carve((size_t)N * 128);
    float*         fin      = (float*)carve((size_t)N * 3 * 4);
    ushortT*       Wt0      = (ushortT*)carve((size_t)128 * 64 * 2);
    ushortT*       Wt1      = (ushortT*)carve((size_t)128 * 256 * 2);
    ushortT*       Wt2      = (ushortT*)carve((size_t)128 * 256 * 2);
    ushortT*       Wa2t     = (ushortT*)carve((size_t)128 * 128 * 2);

    const int gemm_grid = (N + 127) / 128;

    // input/weight prep
    to_bf16_vec<<<(N * 32 / 4 + 255) / 256, 256, 0, stream>>>(x, xbf, N * 32 / 4);
    prep_all<<<(8192 + 65536 + 16384 + 255) / 256, 256, 0, stream>>>(
        Wl0, Wr0, Wl1, Wr1, Wl2, Wr2, Wa2, Wt0, Wt1, Wt2, Wa2t);

    // CSR build (radix-style, precomputed bases)
    hist_pass<<<NBLK, 256, 0, stream>>>(dst, hist_blk, E, NB);
    pbase_scan<<<1, 1024, 0, stream>>>(hist_blk, bstart, pbase, NB, NBLK, E);
    partition_edges<<<NBLK, 256, 0, stream>>>(src, dst, pbase, packed, E, NB);
    bucket_sort<<<NB, 256, 0, stream>>>(packed, bstart, row_start, srcs, N);

    // layer 0 (KH=32): bf16 gather on x; dual-write h0 (bf16 + fp8)
    aggregate_mean_bf16<4><<<(N * 2 + 255) / 256, 256, 0, stream>>>(
        (const uint4*)xbf, aggbf, srcs, row_start, N);
    gemm_mfma<32, true, true><<<gemm_grid, 256, 0, stream>>>(
        aggbf, xbf, Wt0, bl0, (float*)nullptr, hbf0, hf8_0, N);
    // layer 1 (KH=128): fp8 gather on h0; dual-write h1
    aggregate_mean_fp8<<<(N * 4 + 255) / 256, 256, 0, stream>>>(
        (const uint4*)hf8_0, aggbf, srcs, row_start, N);
    gemm_mfma<128, true, true><<<gemm_grid, 256, 0, stream>>>(
        aggbf, hbf0, Wt1, bl1, (float*)nullptr, hbf1, hf8_1, N);
    // layer 2 (KH=128): fp8 gather on h1; fused d1/d3 epilogue -> fin
    aggregate_mean_fp8<<<(N * 4 + 255) / 256, 256, 0, stream>>>(
        (const uint4*)hf8_1, aggbf, srcs, row_start, N);
    gemm_mfma_fin<128><<<gemm_grid, 256, 0, stream>>>(
        aggbf, hbf1, Wt2, bl2, Wfc, bfc, fin, N);

    // head aux MLP (MFMA, register-built A) -> fin[:,1]
    head_mfma<<<gemm_grid, 256, 0, stream>>>(
        Wa2t, Wa1, ba1, ba2, Wao, bao, fin, N);

    // per-graph mean pool
    pool_kernel<<<G, 256, 0, stream>>>(fin, batch, out, N);
}

// Round 9
// 380.196 us; speedup vs baseline: 1.2837x; 1.2837x over previous
//
#include <hip/hip_runtime.h>

#define NR 128        // dst nodes per bucket
#define PART_CH 8192  // edges per hist/partition block
typedef unsigned short ushortT;
typedef __attribute__((ext_vector_type(8))) short short8;
typedef __attribute__((ext_vector_type(4))) float float4v;
typedef __attribute__((ext_vector_type(2))) float float2v;

__device__ __forceinline__ unsigned short f32_to_bf16_rne(float f) {
    unsigned u = __float_as_uint(f);
    unsigned r = (u + 0x7fffu + ((u >> 16) & 1u)) >> 16;
    return (unsigned short)r;
}

__device__ __forceinline__ unsigned char f32_to_fp8(float f) {
    return (unsigned char)(__builtin_amdgcn_cvt_pk_fp8_f32(f, f, 0, false) & 0xff);
}

__device__ __forceinline__ void accum8(float* acc, uint4 v) {
    unsigned u[4] = {v.x, v.y, v.z, v.w};
#pragma unroll
    for (int q = 0; q < 4; q++) {
        acc[2 * q]     += __uint_as_float(u[q] << 16);
        acc[2 * q + 1] += __uint_as_float(u[q] & 0xffff0000u);
    }
}

// 16 fp8 values in a uint4 -> acc[16]
__device__ __forceinline__ void accum16_fp8(float* acc, uint4 v) {
    unsigned u[4] = {v.x, v.y, v.z, v.w};
#pragma unroll
    for (int q = 0; q < 4; q++) {
        float2v lo = __builtin_amdgcn_cvt_pk_f32_fp8(u[q], false);
        float2v hi = __builtin_amdgcn_cvt_pk_f32_fp8(u[q], true);
        acc[4 * q + 0] += lo.x;
        acc[4 * q + 1] += lo.y;
        acc[4 * q + 2] += hi.x;
        acc[4 * q + 3] += hi.y;
    }
}

// ---------------- CSR build: radix-style with precomputed bases ----------------

__launch_bounds__(256)
__global__ void hist_pass(const int* __restrict__ dst, int* __restrict__ hist_blk, int E, int NB) {
    __shared__ int h[1024];
    int t = threadIdx.x;
    for (int j = t; j < 1024; j += 256) h[j] = 0;
    __syncthreads();
    int e0 = blockIdx.x * PART_CH;
    int e1 = min(e0 + PART_CH, E);
    for (int base = e0; base < e1; base += 2048) {
        int idx = base + t;
        int d[8];
        int cnt = 0;
#pragma unroll
        for (int u = 0; u < 8; u++) {
            int e = idx + u * 256;
            if (e < e1) d[cnt++] = dst[e];
        }
        for (int u = 0; u < cnt; u++) atomicAdd(&h[d[u] >> 7], 1);
    }
    __syncthreads();
    int* row = hist_blk + (size_t)blockIdx.x * NB;
    for (int j = t; j < NB; j += 256) row[j] = h[j];
}

// grid-parallel: each thread owns one bucket; walks its column over all block
// histograms (coalesced across threads), writing local exclusive prefixes + total.
__launch_bounds__(256)
__global__ void col_scan(const int* __restrict__ hist_blk, int* __restrict__ pbase,
                         int* __restrict__ btot, int NB, int NBLK) {
    int bucket = blockIdx.x * 256 + threadIdx.x;
    if (bucket >= NB) return;
    int run = 0;
    int b = 0;
    for (; b + 4 <= NBLK; b += 4) {
        int v0 = hist_blk[(size_t)(b + 0) * NB + bucket];
        int v1 = hist_blk[(size_t)(b + 1) * NB + bucket];
        int v2 = hist_blk[(size_t)(b + 2) * NB + bucket];
        int v3 = hist_blk[(size_t)(b + 3) * NB + bucket];
        pbase[(size_t)(b + 0) * NB + bucket] = run;
        pbase[(size_t)(b + 1) * NB + bucket] = run + v0;
        pbase[(size_t)(b + 2) * NB + bucket] = run + v0 + v1;
        pbase[(size_t)(b + 3) * NB + bucket] = run + v0 + v1 + v2;
        run += v0 + v1 + v2 + v3;
    }
    for (; b < NBLK; b++) {
        size_t idx = (size_t)b * NB + bucket;
        int v = hist_blk[idx];
        pbase[idx] = run;
        run += v;
    }
    btot[bucket] = run;
}

// single block: exclusive scan of NB (<=1024) bucket totals -> bstart
__launch_bounds__(1024)
__global__ void bstart_scan(const int* __restrict__ btot, int* __restrict__ bstart, int NB, int E) {
    __shared__ int sh[1024];
    int t = threadIdx.x;
    int tot = (t < NB) ? btot[t] : 0;
    sh[t] = tot;
    __syncthreads();
    for (int off = 1; off < 1024; off <<= 1) {
        int add = (t >= off) ? sh[t - off] : 0;
        __syncthreads();
        sh[t] += add;
        __syncthreads();
    }
    if (t < NB) bstart[t] = sh[t] - tot;
    if (t == 0) bstart[NB] = E;
}

// single pass: scatter packed records using precomputed LDS cursors (no global atomics)
// packed record = src | (dst&127)<<17  (src < 2^17)
__launch_bounds__(256)
__global__ void partition_edges(const int* __restrict__ src, const int* __restrict__ dst,
                                const int* __restrict__ pbase, const int* __restrict__ bstart,
                                unsigned* __restrict__ packed, int E, int NB) {
    __shared__ int cur[1024];
    int t = threadIdx.x, b = blockIdx.x;
    const int* prow = pbase + (size_t)b * NB;
    for (int j = t; j < NB; j += 256) cur[j] = prow[j] + bstart[j];
    __syncthreads();
    int e0 = b * PART_CH;
    int e1 = min(e0 + PART_CH, E);
    for (int base = e0; base < e1; base += 2048) {
        int idx = base + t;
        int d[8], s[8];
        int cnt = 0;
#pragma unroll
        for (int u = 0; u < 8; u++) {
            int e = idx + u * 256;
            if (e < e1) { d[cnt] = dst[e]; s[cnt] = src[e]; cnt++; }
        }
        for (int u = 0; u < cnt; u++) {
            int dd = d[u];
            int pos = atomicAdd(&cur[dd >> 7], 1);
            packed[pos] = (unsigned)s[u] | ((unsigned)(dd & (NR - 1)) << 17);
        }
    }
}

__launch_bounds__(256)
__global__ void bucket_sort(const unsigned* __restrict__ packed, const int* __restrict__ bstart,
                            int* __restrict__ row_start, int* __restrict__ srcs, int N) {
    __shared__ int cnt[NR];
    __shared__ int sc[NR];
    __shared__ int cur[NR];
    int b = blockIdx.x, t = threadIdx.x;
    int nb0 = b * NR;
    int nnode = min(NR, N - nb0);
    int lo = bstart[b], hi = bstart[b + 1];
    if (t < NR) cnt[t] = 0;
    __syncthreads();
    for (int base = lo; base < hi; base += 2048) {
        int idx = base + t;
        unsigned pk[8];
        int c = 0;
#pragma unroll
        for (int u = 0; u < 8; u++) {
            int e = idx + u * 256;
            if (e < hi) pk[c++] = packed[e];
        }
        for (int u = 0; u < c; u++) atomicAdd(&cnt[pk[u] >> 17], 1);
    }
    __syncthreads();
    if (t < NR) sc[t] = cnt[t];
    __syncthreads();
    for (int off = 1; off < NR; off <<= 1) {
        int add = (t >= off && t < NR) ? sc[t - off] : 0;
        __syncthreads();
        if (t < NR) sc[t] += add;
        __syncthreads();
    }
    if (t < nnode) {
        int s = lo + sc[t] - cnt[t];
        row_start[nb0 + t] = s;
        cur[t] = s;
    }
    if (t == 0 && nb0 + nnode == N) row_start[N] = hi;
    __syncthreads();
    for (int base = lo; base < hi; base += 2048) {
        int idx = base + t;
        unsigned pk[8];
        int c = 0;
#pragma unroll
        for (int u = 0; u < 8; u++) {
            int e = idx + u * 256;
            if (e < hi) pk[c++] = packed[e];
        }
        for (int u = 0; u < c; u++) {
            int pos = atomicAdd(&cur[pk[u] >> 17], 1);
            srcs[pos] = (int)(pk[u] & 0x1FFFFu);
        }
    }
}

// ---------------- f32 -> bf16 ----------------

__global__ void to_bf16_vec(const float* __restrict__ in, ushortT* __restrict__ out, int n4) {
    int t = blockIdx.x * 256 + threadIdx.x;
    if (t < n4) {
        float4 v = ((const float4*)in)[t];
        ushort4 o;
        o.x = f32_to_bf16_rne(v.x);
        o.y = f32_to_bf16_rne(v.y);
        o.z = f32_to_bf16_rne(v.z);
        o.w = f32_to_bf16_rne(v.w);
        ((ushort4*)out)[t] = o;
    }
}

// ---------------- all weight preps, one kernel ----------------
// Wt layout: Wt[col][(k + 8*col) % KT] = bf16(Wcat[k][col])

__global__ void prep_all(const float* __restrict__ Wl0, const float* __restrict__ Wr0,
                         const float* __restrict__ Wl1, const float* __restrict__ Wr1,
                         const float* __restrict__ Wl2, const float* __restrict__ Wr2,
                         const float* __restrict__ Wa2,
                         ushortT* __restrict__ Wt0, ushortT* __restrict__ Wt1,
                         ushortT* __restrict__ Wt2, ushortT* __restrict__ Wa2t) {
    int tid = blockIdx.x * 256 + threadIdx.x;
    if (tid < 8192) {  // Wt0: KH=32, KT=64
        int col = tid >> 6, k = tid & 63;
        float v = (k < 32) ? Wl0[k * 128 + col] : Wr0[(k - 32) * 128 + col];
        Wt0[col * 64 + ((k + 8 * col) & 63)] = f32_to_bf16_rne(v);
    } else if (tid < 8192 + 32768) {  // Wt1: KT=256
        int j = tid - 8192;
        int col = j >> 8, k = j & 255;
        float v = (k < 128) ? Wl1[k * 128 + col] : Wr1[(k - 128) * 128 + col];
        Wt1[col * 256 + ((k + 8 * col) & 255)] = f32_to_bf16_rne(v);
    } else if (tid < 8192 + 65536) {  // Wt2: KT=256
        int j = tid - 8192 - 32768;
        int col = j >> 8, k = j & 255;
        float v = (k < 128) ? Wl2[k * 128 + col] : Wr2[(k - 128) * 128 + col];
        Wt2[col * 256 + ((k + 8 * col) & 255)] = f32_to_bf16_rne(v);
    } else if (tid < 8192 + 65536 + 16384) {  // Wa2t: KT=128
        int j = tid - 8192 - 65536;
        int col = j >> 7, k = j & 127;
        Wa2t[col * 128 + ((k + 8 * col) & 127)] = f32_to_bf16_rne(Wa2[k * 128 + col]);
    }
}

// ---------------- aggregation: bf16 input (layer 0, 32 feats) ----------------

template <int CPN>
__launch_bounds__(256)
__global__ void aggregate_mean_bf16(const uint4* __restrict__ hin, ushortT* __restrict__ out,
                                    const int* __restrict__ srcs, const int* __restrict__ rs, int n) {
    constexpr int TPN = CPN / 2;
    int tid = blockIdx.x * 256 + threadIdx.x;
    if (tid >= n * TPN) return;
    int i = tid / TPN;
    int c = tid & (TPN - 1);
    int lo = rs[i], hi = rs[i + 1];
    float acc0[8], acc1[8];
#pragma unroll
    for (int q = 0; q < 8; q++) { acc0[q] = 0.f; acc1[q] = 0.f; }
    int e = lo;
    for (; e + 8 <= hi; e += 8) {
        int s[8];
#pragma unroll
        for (int u = 0; u < 8; u++) s[u] = srcs[e + u];
        uint4 va[8], vb[8];
#pragma unroll
        for (int u = 0; u < 8; u++) {
            va[u] = hin[(size_t)s[u] * CPN + c];
            vb[u] = hin[(size_t)s[u] * CPN + c + TPN];
        }
#pragma unroll
        for (int u = 0; u < 8; u++) { accum8(acc0, va[u]); accum8(acc1, vb[u]); }
    }
    for (; e < hi; ++e) {
        int s = srcs[e];
        accum8(acc0, hin[(size_t)s * CPN + c]);
        accum8(acc1, hin[(size_t)s * CPN + c + TPN]);
    }
    float inv = 1.0f / (float)max(hi - lo, 1);
    uint4 o0, o1;
    o0.x = (unsigned)f32_to_bf16_rne(acc0[0] * inv) | ((unsigned)f32_to_bf16_rne(acc0[1] * inv) << 16);
    o0.y = (unsigned)f32_to_bf16_rne(acc0[2] * inv) | ((unsigned)f32_to_bf16_rne(acc0[3] * inv) << 16);
    o0.z = (unsigned)f32_to_bf16_rne(acc0[4] * inv) | ((unsigned)f32_to_bf16_rne(acc0[5] * inv) << 16);
    o0.w = (unsigned)f32_to_bf16_rne(acc0[6] * inv) | ((unsigned)f32_to_bf16_rne(acc0[7] * inv) << 16);
    o1.x = (unsigned)f32_to_bf16_rne(acc1[0] * inv) | ((unsigned)f32_to_bf16_rne(acc1[1] * inv) << 16);
    o1.y = (unsigned)f32_to_bf16_rne(acc1[2] * inv) | ((unsigned)f32_to_bf16_rne(acc1[3] * inv) << 16);
    o1.z = (unsigned)f32_to_bf16_rne(acc1[4] * inv) | ((unsigned)f32_to_bf16_rne(acc1[5] * inv) << 16);
    o1.w = (unsigned)f32_to_bf16_rne(acc1[6] * inv) | ((unsigned)f32_to_bf16_rne(acc1[7] * inv) << 16);
    ((uint4*)out)[(size_t)i * CPN + c] = o0;
    ((uint4*)out)[(size_t)i * CPN + c + TPN] = o1;
}

// ---------------- aggregation: fp8 input (layers 1/2, 128 feats) ----------------
// row = 128 fp8 = 8 uint4; 8 threads/node, 1 uint4 (16 feats) each; f32 acc; bf16 out.

__launch_bounds__(256)
__global__ void aggregate_mean_fp8(const uint4* __restrict__ hin, ushortT* __restrict__ out,
                                   const int* __restrict__ srcs, const int* __restrict__ rs, int n) {
    int tid = blockIdx.x * 256 + threadIdx.x;
    if (tid >= n * 8) return;
    int i = tid >> 3;
    int c = tid & 7;
    int lo = rs[i], hi = rs[i + 1];
    float acc[16];
#pragma unroll
    for (int q = 0; q < 16; q++) acc[q] = 0.f;
    int e = lo;
    for (; e + 8 <= hi; e += 8) {
        int s[8];
#pragma unroll
        for (int u = 0; u < 8; u++) s[u] = srcs[e + u];
        uint4 v[8];
#pragma unroll
        for (int u = 0; u < 8; u++) v[u] = hin[(size_t)s[u] * 8 + c];
#pragma unroll
        for (int u = 0; u < 8; u++) accum16_fp8(acc, v[u]);
    }
    for (; e + 4 <= hi; e += 4) {
        int s[4];
#pragma unroll
        for (int u = 0; u < 4; u++) s[u] = srcs[e + u];
        uint4 v[4];
#pragma unroll
        for (int u = 0; u < 4; u++) v[u] = hin[(size_t)s[u] * 8 + c];
#pragma unroll
        for (int u = 0; u < 4; u++) accum16_fp8(acc, v[u]);
    }
    for (; e < hi; ++e) accum16_fp8(acc, hin[(size_t)srcs[e] * 8 + c]);
    float inv = 1.0f / (float)max(hi - lo, 1);
    uint4 o0, o1;
    o0.x = (unsigned)f32_to_bf16_rne(acc[0] * inv)  | ((unsigned)f32_to_bf16_rne(acc[1] * inv) << 16);
    o0.y = (unsigned)f32_to_bf16_rne(acc[2] * inv)  | ((unsigned)f32_to_bf16_rne(acc[3] * inv) << 16);
    o0.z = (unsigned)f32_to_bf16_rne(acc[4] * inv)  | ((unsigned)f32_to_bf16_rne(acc[5] * inv) << 16);
    o0.w = (unsigned)f32_to_bf16_rne(acc[6] * inv)  | ((unsigned)f32_to_bf16_rne(acc[7] * inv) << 16);
    o1.x = (unsigned)f32_to_bf16_rne(acc[8] * inv)  | ((unsigned)f32_to_bf16_rne(acc[9] * inv) << 16);
    o1.y = (unsigned)f32_to_bf16_rne(acc[10] * inv) | ((unsigned)f32_to_bf16_rne(acc[11] * inv) << 16);
    o1.z = (unsigned)f32_to_bf16_rne(acc[12] * inv) | ((unsigned)f32_to_bf16_rne(acc[13] * inv) << 16);
    o1.w = (unsigned)f32_to_bf16_rne(acc[14] * inv) | ((unsigned)f32_to_bf16_rne(acc[15] * inv) << 16);
    ((uint4*)out)[(size_t)i * 16 + c * 2]     = o0;
    ((uint4*)out)[(size_t)i * 16 + c * 2 + 1] = o1;
}

// ---------------- MFMA GEMM: out = relu([Am | Ah] @ [Wl;Wr] + bias) --------------------

template <int KH, bool OUT_BF16, bool OUT_FP8>
__launch_bounds__(256, 2)
__global__ void gemm_mfma(const ushortT* __restrict__ Am, const ushortT* __restrict__ Ah,
                          const ushortT* __restrict__ Wt, const float* __restrict__ bias,
                          float* __restrict__ outf, ushortT* __restrict__ outbf,
                          unsigned char* __restrict__ outf8, int n) {
    constexpr int KT = 2 * KH;
    __shared__ ushortT sW[128 * KT];
    int t = threadIdx.x;
    constexpr int TOT16 = 128 * KT * 2 / 16;
    {
        const uint4* Wg = (const uint4*)Wt;
        uint4* Ws = (uint4*)sW;
        for (int j = t; j < TOT16; j += 256) Ws[j] = Wg[j];
    }
    __syncthreads();
    int wv = t >> 6, lane = t & 63;
    int q = lane >> 4, cid = lane & 15;
    int rbase = blockIdx.x * 128 + wv * 32;
    int r0 = rbase + cid, r1 = r0 + 16;
    int r0c = min(r0, n - 1), r1c = min(r1, n - 1);
    float4v acc[2][8];
#pragma unroll
    for (int i = 0; i < 2; i++)
#pragma unroll
        for (int j = 0; j < 8; j++) acc[i][j] = (float4v){0.f, 0.f, 0.f, 0.f};
    int swz = q * 8 + 8 * cid;
#pragma unroll
    for (int ks = 0; ks < KT / 32; ++ks) {
        int kk = ks * 32;
        const ushortT* abase = (kk < KH) ? Am : Ah;
        int kc = (kk < KH) ? kk : kk - KH;
        short8 a0 = *(const short8*)(abase + (size_t)r0c * KH + kc + q * 8);
        short8 a1 = *(const short8*)(abase + (size_t)r1c * KH + kc + q * 8);
#pragma unroll
        for (int j = 0; j < 8; ++j) {
            int col = j * 16 + cid;
            int p = (kk + swz + j * 128) & (KT - 1);
            short8 b = *(const short8*)(sW + col * KT + p);
            acc[0][j] = __builtin_amdgcn_mfma_f32_16x16x32_bf16(a0, b, acc[0][j], 0, 0, 0);
            acc[1][j] = __builtin_amdgcn_mfma_f32_16x16x32_bf16(a1, b, acc[1][j], 0, 0, 0);
        }
    }
    float bo[8];
#pragma unroll
    for (int j = 0; j < 8; ++j) bo[j] = bias[j * 16 + cid];
#pragma unroll
    for (int i = 0; i < 2; ++i) {
#pragma unroll
        for (int rr = 0; rr < 4; ++rr) {
            int row = rbase + i * 16 + q * 4 + rr;
            if (row < n) {
#pragma unroll
                for (int j = 0; j < 8; ++j) {
                    int col = j * 16 + cid;
                    float v = fmaxf(acc[i][j][rr] + bo[j], 0.f);
                    if (OUT_BF16) outbf[(size_t)row * 128 + col] = f32_to_bf16_rne(v);
                    if (OUT_FP8)  outf8[(size_t)row * 128 + col] = f32_to_fp8(v);
                    if (!OUT_BF16 && !OUT_FP8) outf[(size_t)row * 128 + col] = v;
                }
            }
        }
    }
}

// ---- layer-2 variant: h3 never materialized; epilogue computes d1/d3 -> fin[:,0],fin[:,2]

template <int KH>
__launch_bounds__(256, 2)
__global__ void gemm_mfma_fin(const ushortT* __restrict__ Am, const ushortT* __restrict__ Ah,
                              const ushortT* __restrict__ Wt, const float* __restrict__ bias,
                              const float* __restrict__ Wfc, const float* __restrict__ bfc,
                              float* __restrict__ fin, int n) {
    constexpr int KT = 2 * KH;
    __shared__ ushortT sW[128 * KT];
    int t = threadIdx.x;
    constexpr int TOT16 = 128 * KT * 2 / 16;
    {
        const uint4* Wg = (const uint4*)Wt;
        uint4* Ws = (uint4*)sW;
        for (int j = t; j < TOT16; j += 256) Ws[j] = Wg[j];
    }
    __syncthreads();
    int wv = t >> 6, lane = t & 63;
    int q = lane >> 4, cid = lane & 15;
    int rbase = blockIdx.x * 128 + wv * 32;
    int r0 = rbase + cid, r1 = r0 + 16;
    int r0c = min(r0, n - 1), r1c = min(r1, n - 1);
    float4v acc[2][8];
#pragma unroll
    for (int i = 0; i < 2; i++)
#pragma unroll
        for (int j = 0; j < 8; j++) acc[i][j] = (float4v){0.f, 0.f, 0.f, 0.f};
    int swz = q * 8 + 8 * cid;
#pragma unroll
    for (int ks = 0; ks < KT / 32; ++ks) {
        int kk = ks * 32;
        const ushortT* abase = (kk < KH) ? Am : Ah;
        int kc = (kk < KH) ? kk : kk - KH;
        short8 a0 = *(const short8*)(abase + (size_t)r0c * KH + kc + q * 8);
        short8 a1 = *(const short8*)(abase + (size_t)r1c * KH + kc + q * 8);
#pragma unroll
        for (int j = 0; j < 8; ++j) {
            int col = j * 16 + cid;
            int p = (kk + swz + j * 128) & (KT - 1);
            short8 b = *(const short8*)(sW + col * KT + p);
            acc[0][j] = __builtin_amdgcn_mfma_f32_16x16x32_bf16(a0, b, acc[0][j], 0, 0, 0);
            acc[1][j] = __builtin_amdgcn_mfma_f32_16x16x32_bf16(a1, b, acc[1][j], 0, 0, 0);
        }
    }
    float bo[8], w1[8], w3[8];
#pragma unroll
    for (int j = 0; j < 8; ++j) {
        int col = j * 16 + cid;
        bo[j] = bias[col];
        w1[j] = Wfc[col * 3 + 0];
        w3[j] = Wfc[col * 3 + 2];
    }
    float bfc0 = bfc[0], bfc2 = bfc[2];
#pragma unroll
    for (int i = 0; i < 2; ++i) {
#pragma unroll
        for (int rr = 0; rr < 4; ++rr) {
            float p1 = 0.f, p3 = 0.f;
#pragma unroll
            for (int j = 0; j < 8; ++j) {
                float v = fmaxf(acc[i][j][rr] + bo[j], 0.f);
                p1 += v * w1[j];
                p3 += v * w3[j];
            }
            p1 += __shfl_xor(p1, 1, 64); p3 += __shfl_xor(p3, 1, 64);
            p1 += __shfl_xor(p1, 2, 64); p3 += __shfl_xor(p3, 2, 64);
            p1 += __shfl_xor(p1, 4, 64); p3 += __shfl_xor(p3, 4, 64);
            p1 += __shfl_xor(p1, 8, 64); p3 += __shfl_xor(p3, 8, 64);
            int row = rbase + i * 16 + q * 4 + rr;
            if (cid == 0 && row < n) {
                fin[(size_t)row * 3 + 0] = p1 + bfc0;
                fin[(size_t)row * 3 + 2] = p3 + bfc2;
            }
        }
    }
}

// ---------------- head: a1 built in registers + a2 MFMA + Wao reduce -> fin[:,1] -------

__launch_bounds__(256, 4)
__global__ void head_mfma(const ushortT* __restrict__ Wa2t, const float* __restrict__ Wa1,
                          const float* __restrict__ ba1, const float* __restrict__ ba2,
                          const float* __restrict__ Wao, const float* __restrict__ bao,
                          float* __restrict__ fin, int n) {
    __shared__ ushortT sW[128 * 128];   // 32 KB
    __shared__ float sD1[128], sD3[128];
    __shared__ float sWa1a[128], sWa1b[128], sBa1[128];
    int t = threadIdx.x;
    {
        const uint4* Wg = (const uint4*)Wa2t;
        uint4* Ws = (uint4*)sW;
        for (int j = t; j < 2048; j += 256) Ws[j] = Wg[j];
    }
    int rbase = blockIdx.x * 128;
    if (t < 128) {
        sWa1a[t] = Wa1[t];
        sWa1b[t] = Wa1[128 + t];
        sBa1[t] = ba1[t];
        int row = min(rbase + t, n - 1);
        sD1[t] = fin[(size_t)row * 3 + 0];
        sD3[t] = fin[(size_t)row * 3 + 2];
    }
    __syncthreads();
    int wv = t >> 6, lane = t & 63;
    int q = lane >> 4, cid = lane & 15;
    int rl0 = wv * 32 + cid, rl1 = rl0 + 16;
    float d1a = sD1[rl0], d3a = sD3[rl0];
    float d1b = sD1[rl1], d3b = sD3[rl1];
    float4v acc[2][8];
#pragma unroll
    for (int i = 0; i < 2; i++)
#pragma unroll
        for (int j = 0; j < 8; j++) acc[i][j] = (float4v){0.f, 0.f, 0.f, 0.f};
    int swz = q * 8 + 8 * cid;
#pragma unroll
    for (int ks = 0; ks < 4; ++ks) {
        int k0 = ks * 32 + q * 8;
        short8 a0, a1;
#pragma unroll
        for (int j = 0; j < 8; ++j) {
            int k = k0 + j;
            float w0 = sWa1a[k], w1 = sWa1b[k], bb = sBa1[k];
            float v0 = fmaxf(fmaf(d1a, w0, fmaf(d3a, w1, bb)), 0.f);
            float v1 = fmaxf(fmaf(d1b, w0, fmaf(d3b, w1, bb)), 0.f);
            a0[j] = (short)f32_to_bf16_rne(v0);
            a1[j] = (short)f32_to_bf16_rne(v1);
        }
        int p = (ks * 32 + swz) & 127;
#pragma unroll
        for (int j = 0; j < 8; ++j) {
            short8 b = *(const short8*)(sW + (j * 16 + cid) * 128 + p);
            acc[0][j] = __builtin_amdgcn_mfma_f32_16x16x32_bf16(a0, b, acc[0][j], 0, 0, 0);
            acc[1][j] = __builtin_amdgcn_mfma_f32_16x16x32_bf16(a1, b, acc[1][j], 0, 0, 0);
        }
    }
    float b2[8], wo[8];
#pragma unroll
    for (int j = 0; j < 8; ++j) {
        int col = j * 16 + cid;
        b2[j] = ba2[col];
        wo[j] = Wao[col];
    }
    float bao0 = bao[0];
#pragma unroll
    for (int i = 0; i < 2; ++i) {
#pragma unroll
        for (int rr = 0; rr < 4; ++rr) {
            float s = 0.f;
#pragma unroll
            for (int j = 0; j < 8; ++j) s += fmaxf(acc[i][j][rr] + b2[j], 0.f) * wo[j];
            s += __shfl_xor(s, 1, 64);
            s += __shfl_xor(s, 2, 64);
            s += __shfl_xor(s, 4, 64);
            s += __shfl_xor(s, 8, 64);
            int row = rbase + wv * 32 + i * 16 + q * 4 + rr;
            if (cid == 0 && row < n) fin[(size_t)row * 3 + 1] = s + bao0;
        }
    }
}

// ---------------- per-graph mean pool ----------------

__global__ void pool_kernel(const float* __restrict__ fin, const int* __restrict__ batch,
                            float* __restrict__ out, int n) {
    int g = blockIdx.x, t = threadIdx.x;
    int lo = 0, hi = n;
    while (lo < hi) { int mid = (lo + hi) >> 1; if (batch[mid] < g) lo = mid + 1; else hi = mid; }
    int start = lo;
    lo = 0; hi = n;
    while (lo < hi) { int mid = (lo + hi) >> 1; if (batch[mid] < g + 1) lo = mid + 1; else hi = mid; }
    int end = lo;
    float s0 = 0.f, s1 = 0.f, s2 = 0.f;
    for (int i = start + t; i < end; i += 256) {
        s0 += fin[(size_t)i * 3 + 0];
        s1 += fin[(size_t)i * 3 + 1];
        s2 += fin[(size_t)i * 3 + 2];
    }
    __shared__ float r0[256], r1[256], r2[256];
    r0[t] = s0; r1[t] = s1; r2[t] = s2;
    __syncthreads();
    for (int off = 128; off > 0; off >>= 1) {
        if (t < off) { r0[t] += r0[t + off]; r1[t] += r1[t + off]; r2[t] += r2[t + off]; }
        __syncthreads();
    }
    if (t == 0) {
        float c = (float)max(end - start, 1);
        out[g * 3 + 0] = r0[0] / c;
        out[g * 3 + 1] = r1[0] / c;
        out[g * 3 + 2] = r2[0] / c;
    }
}

// ---------------- launch ----------------

extern "C" void kernel_launch(void* const* d_in, const int* in_sizes, int n_in,
                              void* d_out, int out_size, void* d_ws, size_t ws_size,
                              hipStream_t stream) {
    const float* x    = (const float*)d_in[0];
    const int*   ei   = (const int*)d_in[1];
    const int*   batch= (const int*)d_in[2];
    const float* Wl0  = (const float*)d_in[3];
    const float* bl0  = (const float*)d_in[4];
    const float* Wr0  = (const float*)d_in[5];
    const float* Wl1  = (const float*)d_in[6];
    const float* bl1  = (const float*)d_in[7];
    const float* Wr1  = (const float*)d_in[8];
    const float* Wl2  = (const float*)d_in[9];
    const float* bl2  = (const float*)d_in[10];
    const float* Wr2  = (const float*)d_in[11];
    const float* Wfc  = (const float*)d_in[12];
    const float* bfc  = (const float*)d_in[13];
    const float* Wa1  = (const float*)d_in[14];
    const float* ba1  = (const float*)d_in[15];
    const float* Wa2  = (const float*)d_in[16];
    const float* ba2  = (const float*)d_in[17];
    const float* Wao  = (const float*)d_in[18];
    const float* bao  = (const float*)d_in[19];

    const int N = in_sizes[0] / 32;
    const int E = in_sizes[1] / 2;
    const int G = out_size / 3;
    const int* src = ei;
    const int* dst = ei + E;
    float* out = (float*)d_out;
    const int NB = (N + NR - 1) / NR;
    const int NBLK = (E + PART_CH - 1) / PART_CH;

    char* p = (char*)d_ws;
    auto carve = [&](size_t bytes) {
        void* r = (void*)p;
        p += (bytes + 255) & ~(size_t)255;
        return r;
    };
    int*           hist_blk = (int*)carve((size_t)NBLK * NB * 4);
    int*           pbase    = (int*)carve((size_t)NBLK * NB * 4);
    int*           btot     = (int*)carve((size_t)NB * 4);
    int*           bstart   = (int*)carve((size_t)(NB + 1) * 4);
    int*           row_start= (int*)carve((size_t)(N + 1) * 4);
    unsigned*      packed   = (unsigned*)carve((size_t)E * 4);
    int*           srcs     = (int*)carve((size_t)E * 4);
    ushortT*       aggbf    = (ushortT*)carve((size_t)N * 128 * 2);
    ushortT*       xbf      = (ushortT*)carve((size_t)N * 32 * 2);
    ushortT*       hbf0     = (ushortT*)carve((size_t)N * 128 * 2);
    ushortT*       hbf1     = (ushortT*)carve((size_t)N * 128 * 2);
    unsigned char* hf8_0    = (unsigned char*)carve((size_t)N * 128);
    unsigned char* hf8_1    = (unsigned char*)carve((size_t)N * 128);
    float*         fin      = (float*)carve((size_t)N * 3 * 4);
    ushortT*       Wt0      = (ushortT*)carve((size_t)128 * 64 * 2);
    ushortT*       Wt1      = (ushortT*)carve((size_t)128 * 256 * 2);
    ushortT*       Wt2      = (ushortT*)carve((size_t)128 * 256 * 2);
    ushortT*       Wa2t     = (ushortT*)carve((size_t)128 * 128 * 2);

    const int gemm_grid = (N + 127) / 128;

    // input/weight prep
    to_bf16_vec<<<(N * 32 / 4 + 255) / 256, 256, 0, stream>>>(x, xbf, N * 32 / 4);
    prep_all<<<(8192 + 65536 + 16384 + 255) / 256, 256, 0, stream>>>(
        Wl0, Wr0, Wl1, Wr1, Wl2, Wr2, Wa2, Wt0, Wt1, Wt2, Wa2t);

    // CSR build (radix-style, parallel scans, no global atomics)
    hist_pass<<<NBLK, 256, 0, stream>>>(dst, hist_blk, E, NB);
    col_scan<<<(NB + 255) / 256, 256, 0, stream>>>(hist_blk, pbase, btot, NB, NBLK);
    bstart_scan<<<1, 1024, 0, stream>>>(btot, bstart, NB, E);
    partition_edges<<<NBLK, 256, 0, stream>>>(src, dst, pbase, bstart, packed, E, NB);
    bucket_sort<<<NB, 256, 0, stream>>>(packed, bstart, row_start, srcs, N);

    // layer 0 (KH=32): bf16 gather on x; dual-write h0 (bf16 + fp8)
    aggregate_mean_bf16<4><<<(N * 2 + 255) / 256, 256, 0, stream>>>(
        (const uint4*)xbf, aggbf, srcs, row_start, N);
    gemm_mfma<32, true, true><<<gemm_grid, 256, 0, stream>>>(
        aggbf, xbf, Wt0, bl0, (float*)nullptr, hbf0, hf8_0, N);
    // layer 1 (KH=128): fp8 gather on h0; dual-write h1
    aggregate_mean_fp8<<<(N * 8 + 255) / 256, 256, 0, stream>>>(
        (const uint4*)hf8_0, aggbf, srcs, row_start, N);
    gemm_mfma<128, true, true><<<gemm_grid, 256, 0, stream>>>(
        aggbf, hbf0, Wt1, bl1, (float*)nullptr, hbf1, hf8_1, N);
    // layer 2 (KH=128): fp8 gather on h1; fused d1/d3 epilogue -> fin
    aggregate_mean_fp8<<<(N * 8 + 255) / 256, 256, 0, stream>>>(
        (const uint4*)hf8_1, aggbf, srcs, row_start, N);
    gemm_mfma_fin<128><<<gemm_grid, 256, 0, stream>>>(
        aggbf, hbf1, Wt2, bl2, Wfc, bfc, fin, N);

    // head aux MLP (MFMA, register-built A) -> fin[:,1]
    head_mfma<<<gemm_grid, 256, 0, stream>>>(
        Wa2t, Wa1, ba1, ba2, Wao, bao, fin, N);

    // per-graph mean pool
    pool_kernel<<<G, 256, 0, stream>>>(fin, batch, out, N);
}

// Round 10
// 376.344 us; speedup vs baseline: 1.2968x; 1.0102x over previous
//
#include <hip/hip_runtime.h>

#define NR 256         // dst nodes per bucket
#define PART_CH 16384  // edges per hist/partition block
typedef unsigned short ushortT;
typedef __attribute__((ext_vector_type(8))) short short8;
typedef __attribute__((ext_vector_type(4))) float float4v;
typedef __attribute__((ext_vector_type(2))) float float2v;

__device__ __forceinline__ unsigned short f32_to_bf16_rne(float f) {
    unsigned u = __float_as_uint(f);
    unsigned r = (u + 0x7fffu + ((u >> 16) & 1u)) >> 16;
    return (unsigned short)r;
}

__device__ __forceinline__ unsigned char f32_to_fp8(float f) {
    return (unsigned char)(__builtin_amdgcn_cvt_pk_fp8_f32(f, f, 0, false) & 0xff);
}

__device__ __forceinline__ void accum8(float* acc, uint4 v) {
    unsigned u[4] = {v.x, v.y, v.z, v.w};
#pragma unroll
    for (int q = 0; q < 4; q++) {
        acc[2 * q]     += __uint_as_float(u[q] << 16);
        acc[2 * q + 1] += __uint_as_float(u[q] & 0xffff0000u);
    }
}

// 16 fp8 values in a uint4 -> acc[16]
__device__ __forceinline__ void accum16_fp8(float* acc, uint4 v) {
    unsigned u[4] = {v.x, v.y, v.z, v.w};
#pragma unroll
    for (int q = 0; q < 4; q++) {
        float2v lo = __builtin_amdgcn_cvt_pk_f32_fp8(u[q], false);
        float2v hi = __builtin_amdgcn_cvt_pk_f32_fp8(u[q], true);
        acc[4 * q + 0] += lo.x;
        acc[4 * q + 1] += lo.y;
        acc[4 * q + 2] += hi.x;
        acc[4 * q + 3] += hi.y;
    }
}

// ---------------- CSR build: radix-style with precomputed bases ----------------

__launch_bounds__(256)
__global__ void hist_pass(const int* __restrict__ dst, int* __restrict__ hist_blk, int E, int NB) {
    __shared__ int h[512];
    int t = threadIdx.x;
    for (int j = t; j < 512; j += 256) h[j] = 0;
    __syncthreads();
    int e0 = blockIdx.x * PART_CH;
    int e1 = min(e0 + PART_CH, E);
    for (int base = e0; base < e1; base += 2048) {
        int idx = base + t;
        int d[8];
        int cnt = 0;
#pragma unroll
        for (int u = 0; u < 8; u++) {
            int e = idx + u * 256;
            if (e < e1) d[cnt++] = dst[e];
        }
        for (int u = 0; u < cnt; u++) atomicAdd(&h[d[u] >> 8], 1);
    }
    __syncthreads();
    int* row = hist_blk + (size_t)blockIdx.x * NB;
    for (int j = t; j < NB; j += 256) row[j] = h[j];
}

// grid-parallel: each thread owns one bucket; walks its column over all block
// histograms (coalesced across threads), writing local exclusive prefixes + total.
__launch_bounds__(256)
__global__ void col_scan(const int* __restrict__ hist_blk, int* __restrict__ pbase,
                         int* __restrict__ btot, int NB, int NBLK) {
    int bucket = blockIdx.x * 256 + threadIdx.x;
    if (bucket >= NB) return;
    int run = 0;
    int b = 0;
    for (; b + 4 <= NBLK; b += 4) {
        int v0 = hist_blk[(size_t)(b + 0) * NB + bucket];
        int v1 = hist_blk[(size_t)(b + 1) * NB + bucket];
        int v2 = hist_blk[(size_t)(b + 2) * NB + bucket];
        int v3 = hist_blk[(size_t)(b + 3) * NB + bucket];
        pbase[(size_t)(b + 0) * NB + bucket] = run;
        pbase[(size_t)(b + 1) * NB + bucket] = run + v0;
        pbase[(size_t)(b + 2) * NB + bucket] = run + v0 + v1;
        pbase[(size_t)(b + 3) * NB + bucket] = run + v0 + v1 + v2;
        run += v0 + v1 + v2 + v3;
    }
    for (; b < NBLK; b++) {
        size_t idx = (size_t)b * NB + bucket;
        int v = hist_blk[idx];
        pbase[idx] = run;
        run += v;
    }
    btot[bucket] = run;
}

// single block (512 thr): exclusive scan of NB (<=512) bucket totals -> bstart
__launch_bounds__(512)
__global__ void bstart_scan(const int* __restrict__ btot, int* __restrict__ bstart, int NB, int E) {
    __shared__ int sh[512];
    int t = threadIdx.x;
    int tot = (t < NB) ? btot[t] : 0;
    sh[t] = tot;
    __syncthreads();
    for (int off = 1; off < 512; off <<= 1) {
        int add = (t >= off) ? sh[t - off] : 0;
        __syncthreads();
        sh[t] += add;
        __syncthreads();
    }
    if (t < NB) bstart[t] = sh[t] - tot;
    if (t == 0) bstart[NB] = E;
}

// single pass: scatter packed records using precomputed LDS cursors (no global atomics)
// packed record = src | (dst & (NR-1)) << 17   (src < 2^17, NR-1 fits 8 bits)
__launch_bounds__(256)
__global__ void partition_edges(const int* __restrict__ src, const int* __restrict__ dst,
                                const int* __restrict__ pbase, const int* __restrict__ bstart,
                                unsigned* __restrict__ packed, int E, int NB) {
    __shared__ int cur[512];
    int t = threadIdx.x, b = blockIdx.x;
    const int* prow = pbase + (size_t)b * NB;
    for (int j = t; j < NB; j += 256) cur[j] = prow[j] + bstart[j];
    __syncthreads();
    int e0 = b * PART_CH;
    int e1 = min(e0 + PART_CH, E);
    for (int base = e0; base < e1; base += 2048) {
        int idx = base + t;
        int d[8], s[8];
        int cnt = 0;
#pragma unroll
        for (int u = 0; u < 8; u++) {
            int e = idx + u * 256;
            if (e < e1) { d[cnt] = dst[e]; s[cnt] = src[e]; cnt++; }
        }
        for (int u = 0; u < cnt; u++) {
            int dd = d[u];
            int pos = atomicAdd(&cur[dd >> 8], 1);
            packed[pos] = (unsigned)s[u] | ((unsigned)(dd & (NR - 1)) << 17);
        }
    }
}

__launch_bounds__(256)
__global__ void bucket_sort(const unsigned* __restrict__ packed, const int* __restrict__ bstart,
                            int* __restrict__ row_start, int* __restrict__ srcs, int N) {
    __shared__ int cnt[NR];
    __shared__ int sc[NR];
    __shared__ int cur[NR];
    int b = blockIdx.x, t = threadIdx.x;
    int nb0 = b * NR;
    int nnode = min(NR, N - nb0);
    int lo = bstart[b], hi = bstart[b + 1];
    cnt[t] = 0;
    if (t + 256 < NR) cnt[t + 256] = 0;
    __syncthreads();
    for (int base = lo; base < hi; base += 2048) {
        int idx = base + t;
        unsigned pk[8];
        int c = 0;
#pragma unroll
        for (int u = 0; u < 8; u++) {
            int e = idx + u * 256;
            if (e < hi) pk[c++] = packed[e];
        }
        for (int u = 0; u < c; u++) atomicAdd(&cnt[pk[u] >> 17], 1);
    }
    __syncthreads();
    sc[t] = cnt[t];
    __syncthreads();
    for (int off = 1; off < NR; off <<= 1) {
        int add = (t >= off) ? sc[t - off] : 0;
        __syncthreads();
        sc[t] += add;
        __syncthreads();
    }
    if (t < nnode) {
        int s = lo + sc[t] - cnt[t];
        row_start[nb0 + t] = s;
        cur[t] = s;
    }
    if (t == 0 && nb0 + nnode == N) row_start[N] = hi;
    __syncthreads();
    for (int base = lo; base < hi; base += 2048) {
        int idx = base + t;
        unsigned pk[8];
        int c = 0;
#pragma unroll
        for (int u = 0; u < 8; u++) {
            int e = idx + u * 256;
            if (e < hi) pk[c++] = packed[e];
        }
        for (int u = 0; u < c; u++) {
            int pos = atomicAdd(&cur[pk[u] >> 17], 1);
            srcs[pos] = (int)(pk[u] & 0x1FFFFu);
        }
    }
}

// ---------------- fused prep: x -> bf16 + all weight transposes ----------------
// Wt layout: Wt[col][(k + 8*col) % KT] = bf16(Wcat[k][col])

__global__ void prep_fused(const float* __restrict__ x, ushortT* __restrict__ xbf, int n4,
                           const float* __restrict__ Wl0, const float* __restrict__ Wr0,
                           const float* __restrict__ Wl1, const float* __restrict__ Wr1,
                           const float* __restrict__ Wl2, const float* __restrict__ Wr2,
                           const float* __restrict__ Wa2,
                           ushortT* __restrict__ Wt0, ushortT* __restrict__ Wt1,
                           ushortT* __restrict__ Wt2, ushortT* __restrict__ Wa2t) {
    int tid0 = blockIdx.x * 256 + threadIdx.x;
    if (tid0 < n4) {
        float4 v = ((const float4*)x)[tid0];
        ushort4 o;
        o.x = f32_to_bf16_rne(v.x);
        o.y = f32_to_bf16_rne(v.y);
        o.z = f32_to_bf16_rne(v.z);
        o.w = f32_to_bf16_rne(v.w);
        ((ushort4*)xbf)[tid0] = o;
        return;
    }
    int tid = tid0 - n4;
    if (tid < 8192) {  // Wt0: KH=32, KT=64
        int col = tid >> 6, k = tid & 63;
        float v = (k < 32) ? Wl0[k * 128 + col] : Wr0[(k - 32) * 128 + col];
        Wt0[col * 64 + ((k + 8 * col) & 63)] = f32_to_bf16_rne(v);
    } else if (tid < 8192 + 32768) {  // Wt1: KT=256
        int j = tid - 8192;
        int col = j >> 8, k = j & 255;
        float v = (k < 128) ? Wl1[k * 128 + col] : Wr1[(k - 128) * 128 + col];
        Wt1[col * 256 + ((k + 8 * col) & 255)] = f32_to_bf16_rne(v);
    } else if (tid < 8192 + 65536) {  // Wt2: KT=256
        int j = tid - 8192 - 32768;
        int col = j >> 8, k = j & 255;
        float v = (k < 128) ? Wl2[k * 128 + col] : Wr2[(k - 128) * 128 + col];
        Wt2[col * 256 + ((k + 8 * col) & 255)] = f32_to_bf16_rne(v);
    } else if (tid < 8192 + 65536 + 16384) {  // Wa2t: KT=128
        int j = tid - 8192 - 65536;
        int col = j >> 7, k = j & 127;
        Wa2t[col * 128 + ((k + 8 * col) & 127)] = f32_to_bf16_rne(Wa2[k * 128 + col]);
    }
}

// ---------------- aggregation: bf16 input (layer 0, 32 feats) ----------------

template <int CPN>
__launch_bounds__(256)
__global__ void aggregate_mean_bf16(const uint4* __restrict__ hin, ushortT* __restrict__ out,
                                    const int* __restrict__ srcs, const int* __restrict__ rs, int n) {
    constexpr int TPN = CPN / 2;
    int tid = blockIdx.x * 256 + threadIdx.x;
    if (tid >= n * TPN) return;
    int i = tid / TPN;
    int c = tid & (TPN - 1);
    int lo = rs[i], hi = rs[i + 1];
    float acc0[8], acc1[8];
#pragma unroll
    for (int q = 0; q < 8; q++) { acc0[q] = 0.f; acc1[q] = 0.f; }
    int e = lo;
    for (; e + 8 <= hi; e += 8) {
        int s[8];
#pragma unroll
        for (int u = 0; u < 8; u++) s[u] = srcs[e + u];
        uint4 va[8], vb[8];
#pragma unroll
        for (int u = 0; u < 8; u++) {
            va[u] = hin[(size_t)s[u] * CPN + c];
            vb[u] = hin[(size_t)s[u] * CPN + c + TPN];
        }
#pragma unroll
        for (int u = 0; u < 8; u++) { accum8(acc0, va[u]); accum8(acc1, vb[u]); }
    }
    for (; e < hi; ++e) {
        int s = srcs[e];
        accum8(acc0, hin[(size_t)s * CPN + c]);
        accum8(acc1, hin[(size_t)s * CPN + c + TPN]);
    }
    float inv = 1.0f / (float)max(hi - lo, 1);
    uint4 o0, o1;
    o0.x = (unsigned)f32_to_bf16_rne(acc0[0] * inv) | ((unsigned)f32_to_bf16_rne(acc0[1] * inv) << 16);
    o0.y = (unsigned)f32_to_bf16_rne(acc0[2] * inv) | ((unsigned)f32_to_bf16_rne(acc0[3] * inv) << 16);
    o0.z = (unsigned)f32_to_bf16_rne(acc0[4] * inv) | ((unsigned)f32_to_bf16_rne(acc0[5] * inv) << 16);
    o0.w = (unsigned)f32_to_bf16_rne(acc0[6] * inv) | ((unsigned)f32_to_bf16_rne(acc0[7] * inv) << 16);
    o1.x = (unsigned)f32_to_bf16_rne(acc1[0] * inv) | ((unsigned)f32_to_bf16_rne(acc1[1] * inv) << 16);
    o1.y = (unsigned)f32_to_bf16_rne(acc1[2] * inv) | ((unsigned)f32_to_bf16_rne(acc1[3] * inv) << 16);
    o1.z = (unsigned)f32_to_bf16_rne(acc1[4] * inv) | ((unsigned)f32_to_bf16_rne(acc1[5] * inv) << 16);
    o1.w = (unsigned)f32_to_bf16_rne(acc1[6] * inv) | ((unsigned)f32_to_bf16_rne(acc1[7] * inv) << 16);
    ((uint4*)out)[(size_t)i * CPN + c] = o0;
    ((uint4*)out)[(size_t)i * CPN + c + TPN] = o1;
}

// ---------------- aggregation: fp8 input (layers 1/2, 128 feats) ----------------
// row = 128 fp8 = 8 uint4; 8 threads/node, 1 uint4 (16 feats) each; f32 acc; bf16 out.

__launch_bounds__(256)
__global__ void aggregate_mean_fp8(const uint4* __restrict__ hin, ushortT* __restrict__ out,
                                   const int* __restrict__ srcs, const int* __restrict__ rs, int n) {
    int tid = blockIdx.x * 256 + threadIdx.x;
    if (tid >= n * 8) return;
    int i = tid >> 3;
    int c = tid & 7;
    int lo = rs[i], hi = rs[i + 1];
    float acc[16];
#pragma unroll
    for (int q = 0; q < 16; q++) acc[q] = 0.f;
    int e = lo;
    for (; e + 8 <= hi; e += 8) {
        int s[8];
#pragma unroll
        for (int u = 0; u < 8; u++) s[u] = srcs[e + u];
        uint4 v[8];
#pragma unroll
        for (int u = 0; u < 8; u++) v[u] = hin[(size_t)s[u] * 8 + c];
#pragma unroll
        for (int u = 0; u < 8; u++) accum16_fp8(acc, v[u]);
    }
    for (; e + 4 <= hi; e += 4) {
        int s[4];
#pragma unroll
        for (int u = 0; u < 4; u++) s[u] = srcs[e + u];
        uint4 v[4];
#pragma unroll
        for (int u = 0; u < 4; u++) v[u] = hin[(size_t)s[u] * 8 + c];
#pragma unroll
        for (int u = 0; u < 4; u++) accum16_fp8(acc, v[u]);
    }
    for (; e < hi; ++e) accum16_fp8(acc, hin[(size_t)srcs[e] * 8 + c]);
    float inv = 1.0f / (float)max(hi - lo, 1);
    uint4 o0, o1;
    o0.x = (unsigned)f32_to_bf16_rne(acc[0] * inv)  | ((unsigned)f32_to_bf16_rne(acc[1] * inv) << 16);
    o0.y = (unsigned)f32_to_bf16_rne(acc[2] * inv)  | ((unsigned)f32_to_bf16_rne(acc[3] * inv) << 16);
    o0.z = (unsigned)f32_to_bf16_rne(acc[4] * inv)  | ((unsigned)f32_to_bf16_rne(acc[5] * inv) << 16);
    o0.w = (unsigned)f32_to_bf16_rne(acc[6] * inv)  | ((unsigned)f32_to_bf16_rne(acc[7] * inv) << 16);
    o1.x = (unsigned)f32_to_bf16_rne(acc[8] * inv)  | ((unsigned)f32_to_bf16_rne(acc[9] * inv) << 16);
    o1.y = (unsigned)f32_to_bf16_rne(acc[10] * inv) | ((unsigned)f32_to_bf16_rne(acc[11] * inv) << 16);
    o1.z = (unsigned)f32_to_bf16_rne(acc[12] * inv) | ((unsigned)f32_to_bf16_rne(acc[13] * inv) << 16);
    o1.w = (unsigned)f32_to_bf16_rne(acc[14] * inv) | ((unsigned)f32_to_bf16_rne(acc[15] * inv) << 16);
    ((uint4*)out)[(size_t)i * 16 + c * 2]     = o0;
    ((uint4*)out)[(size_t)i * 16 + c * 2 + 1] = o1;
}

// ---------------- MFMA GEMM: out = relu([Am | Ah] @ [Wl;Wr] + bias) --------------------

template <int KH, bool OUT_BF16, bool OUT_FP8>
__launch_bounds__(256, 2)
__global__ void gemm_mfma(const ushortT* __restrict__ Am, const ushortT* __restrict__ Ah,
                          const ushortT* __restrict__ Wt, const float* __restrict__ bias,
                          float* __restrict__ outf, ushortT* __restrict__ outbf,
                          unsigned char* __restrict__ outf8, int n) {
    constexpr int KT = 2 * KH;
    __shared__ ushortT sW[128 * KT];
    int t = threadIdx.x;
    constexpr int TOT16 = 128 * KT * 2 / 16;
    {
        const uint4* Wg = (const uint4*)Wt;
        uint4* Ws = (uint4*)sW;
        for (int j = t; j < TOT16; j += 256) Ws[j] = Wg[j];
    }
    __syncthreads();
    int wv = t >> 6, lane = t & 63;
    int q = lane >> 4, cid = lane & 15;
    int rbase = blockIdx.x * 128 + wv * 32;
    int r0 = rbase + cid, r1 = r0 + 16;
    int r0c = min(r0, n - 1), r1c = min(r1, n - 1);
    float4v acc[2][8];
#pragma unroll
    for (int i = 0; i < 2; i++)
#pragma unroll
        for (int j = 0; j < 8; j++) acc[i][j] = (float4v){0.f, 0.f, 0.f, 0.f};
    int swz = q * 8 + 8 * cid;
#pragma unroll
    for (int ks = 0; ks < KT / 32; ++ks) {
        int kk = ks * 32;
        const ushortT* abase = (kk < KH) ? Am : Ah;
        int kc = (kk < KH) ? kk : kk - KH;
        short8 a0 = *(const short8*)(abase + (size_t)r0c * KH + kc + q * 8);
        short8 a1 = *(const short8*)(abase + (size_t)r1c * KH + kc + q * 8);
#pragma unroll
        for (int j = 0; j < 8; ++j) {
            int col = j * 16 + cid;
            int p = (kk + swz + j * 128) & (KT - 1);
            short8 b = *(const short8*)(sW + col * KT + p);
            acc[0][j] = __builtin_amdgcn_mfma_f32_16x16x32_bf16(a0, b, acc[0][j], 0, 0, 0);
            acc[1][j] = __builtin_amdgcn_mfma_f32_16x16x32_bf16(a1, b, acc[1][j], 0, 0, 0);
        }
    }
    float bo[8];
#pragma unroll
    for (int j = 0; j < 8; ++j) bo[j] = bias[j * 16 + cid];
#pragma unroll
    for (int i = 0; i < 2; ++i) {
#pragma unroll
        for (int rr = 0; rr < 4; ++rr) {
            int row = rbase + i * 16 + q * 4 + rr;
            if (row < n) {
#pragma unroll
                for (int j = 0; j < 8; ++j) {
                    int col = j * 16 + cid;
                    float v = fmaxf(acc[i][j][rr] + bo[j], 0.f);
                    if (OUT_BF16) outbf[(size_t)row * 128 + col] = f32_to_bf16_rne(v);
                    if (OUT_FP8)  outf8[(size_t)row * 128 + col] = f32_to_fp8(v);
                    if (!OUT_BF16 && !OUT_FP8) outf[(size_t)row * 128 + col] = v;
                }
            }
        }
    }
}

// ---- layer-2 variant: h3 never materialized; epilogue computes d1/d3 -> fin[:,0],fin[:,2]

template <int KH>
__launch_bounds__(256, 2)
__global__ void gemm_mfma_fin(const ushortT* __restrict__ Am, const ushortT* __restrict__ Ah,
                              const ushortT* __restrict__ Wt, const float* __restrict__ bias,
                              const float* __restrict__ Wfc, const float* __restrict__ bfc,
                              float* __restrict__ fin, int n) {
    constexpr int KT = 2 * KH;
    __shared__ ushortT sW[128 * KT];
    int t = threadIdx.x;
    constexpr int TOT16 = 128 * KT * 2 / 16;
    {
        const uint4* Wg = (const uint4*)Wt;
        uint4* Ws = (uint4*)sW;
        for (int j = t; j < TOT16; j += 256) Ws[j] = Wg[j];
    }
    __syncthreads();
    int wv = t >> 6, lane = t & 63;
    int q = lane >> 4, cid = lane & 15;
    int rbase = blockIdx.x * 128 + wv * 32;
    int r0 = rbase + cid, r1 = r0 + 16;
    int r0c = min(r0, n - 1), r1c = min(r1, n - 1);
    float4v acc[2][8];
#pragma unroll
    for (int i = 0; i < 2; i++)
#pragma unroll
        for (int j = 0; j < 8; j++) acc[i][j] = (float4v){0.f, 0.f, 0.f, 0.f};
    int swz = q * 8 + 8 * cid;
#pragma unroll
    for (int ks = 0; ks < KT / 32; ++ks) {
        int kk = ks * 32;
        const ushortT* abase = (kk < KH) ? Am : Ah;
        int kc = (kk < KH) ? kk : kk - KH;
        short8 a0 = *(const short8*)(abase + (size_t)r0c * KH + kc + q * 8);
        short8 a1 = *(const short8*)(abase + (size_t)r1c * KH + kc + q * 8);
#pragma unroll
        for (int j = 0; j < 8; ++j) {
            int col = j * 16 + cid;
            int p = (kk + swz + j * 128) & (KT - 1);
            short8 b = *(const short8*)(sW + col * KT + p);
            acc[0][j] = __builtin_amdgcn_mfma_f32_16x16x32_bf16(a0, b, acc[0][j], 0, 0, 0);
            acc[1][j] = __builtin_amdgcn_mfma_f32_16x16x32_bf16(a1, b, acc[1][j], 0, 0, 0);
        }
    }
    float bo[8], w1[8], w3[8];
#pragma unroll
    for (int j = 0; j < 8; ++j) {
        int col = j * 16 + cid;
        bo[j] = bias[col];
        w1[j] = Wfc[col * 3 + 0];
        w3[j] = Wfc[col * 3 + 2];
    }
    float bfc0 = bfc[0], bfc2 = bfc[2];
#pragma unroll
    for (int i = 0; i < 2; ++i) {
#pragma unroll
        for (int rr = 0; rr < 4; ++rr) {
            float p1 = 0.f, p3 = 0.f;
#pragma unroll
            for (int j = 0; j < 8; ++j) {
                float v = fmaxf(acc[i][j][rr] + bo[j], 0.f);
                p1 += v * w1[j];
                p3 += v * w3[j];
            }
            p1 += __shfl_xor(p1, 1, 64); p3 += __shfl_xor(p3, 1, 64);
            p1 += __shfl_xor(p1, 2, 64); p3 += __shfl_xor(p3, 2, 64);
            p1 += __shfl_xor(p1, 4, 64); p3 += __shfl_xor(p3, 4, 64);
            p1 += __shfl_xor(p1, 8, 64); p3 += __shfl_xor(p3, 8, 64);
            int row = rbase + i * 16 + q * 4 + rr;
            if (cid == 0 && row < n) {
                fin[(size_t)row * 3 + 0] = p1 + bfc0;
                fin[(size_t)row * 3 + 2] = p3 + bfc2;
            }
        }
    }
}

// ---------------- head: a1 built in registers + a2 MFMA + Wao reduce -> fin[:,1] -------

__launch_bounds__(256, 4)
__global__ void head_mfma(const ushortT* __restrict__ Wa2t, const float* __restrict__ Wa1,
                          const float* __restrict__ ba1, const float* __restrict__ ba2,
                          const float* __restrict__ Wao, const float* __restrict__ bao,
                          float* __restrict__ fin, int n) {
    __shared__ ushortT sW[128 * 128];   // 32 KB
    __shared__ float sD1[128], sD3[128];
    __shared__ float sWa1a[128], sWa1b[128], sBa1[128];
    int t = threadIdx.x;
    {
        const uint4* Wg = (const uint4*)Wa2t;
        uint4* Ws = (uint4*)sW;
        for (int j = t; j < 2048; j += 256) Ws[j] = Wg[j];
    }
    int rbase = blockIdx.x * 128;
    if (t < 128) {
        sWa1a[t] = Wa1[t];
        sWa1b[t] = Wa1[128 + t];
        sBa1[t] = ba1[t];
        int row = min(rbase + t, n - 1);
        sD1[t] = fin[(size_t)row * 3 + 0];
        sD3[t] = fin[(size_t)row * 3 + 2];
    }
    __syncthreads();
    int wv = t >> 6, lane = t & 63;
    int q = lane >> 4, cid = lane & 15;
    int rl0 = wv * 32 + cid, rl1 = rl0 + 16;
    float d1a = sD1[rl0], d3a = sD3[rl0];
    float d1b = sD1[rl1], d3b = sD3[rl1];
    float4v acc[2][8];
#pragma unroll
    for (int i = 0; i < 2; i++)
#pragma unroll
        for (int j = 0; j < 8; j++) acc[i][j] = (float4v){0.f, 0.f, 0.f, 0.f};
    int swz = q * 8 + 8 * cid;
#pragma unroll
    for (int ks = 0; ks < 4; ++ks) {
        int k0 = ks * 32 + q * 8;
        short8 a0, a1;
#pragma unroll
        for (int j = 0; j < 8; ++j) {
            int k = k0 + j;
            float w0 = sWa1a[k], w1 = sWa1b[k], bb = sBa1[k];
            float v0 = fmaxf(fmaf(d1a, w0, fmaf(d3a, w1, bb)), 0.f);
            float v1 = fmaxf(fmaf(d1b, w0, fmaf(d3b, w1, bb)), 0.f);
            a0[j] = (short)f32_to_bf16_rne(v0);
            a1[j] = (short)f32_to_bf16_rne(v1);
        }
        int p = (ks * 32 + swz) & 127;
#pragma unroll
        for (int j = 0; j < 8; ++j) {
            short8 b = *(const short8*)(sW + (j * 16 + cid) * 128 + p);
            acc[0][j] = __builtin_amdgcn_mfma_f32_16x16x32_bf16(a0, b, acc[0][j], 0, 0, 0);
            acc[1][j] = __builtin_amdgcn_mfma_f32_16x16x32_bf16(a1, b, acc[1][j], 0, 0, 0);
        }
    }
    float b2[8], wo[8];
#pragma unroll
    for (int j = 0; j < 8; ++j) {
        int col = j * 16 + cid;
        b2[j] = ba2[col];
        wo[j] = Wao[col];
    }
    float bao0 = bao[0];
#pragma unroll
    for (int i = 0; i < 2; ++i) {
#pragma unroll
        for (int rr = 0; rr < 4; ++rr) {
            float s = 0.f;
#pragma unroll
            for (int j = 0; j < 8; ++j) s += fmaxf(acc[i][j][rr] + b2[j], 0.f) * wo[j];
            s += __shfl_xor(s, 1, 64);
            s += __shfl_xor(s, 2, 64);
            s += __shfl_xor(s, 4, 64);
            s += __shfl_xor(s, 8, 64);
            int row = rbase + wv * 32 + i * 16 + q * 4 + rr;
            if (cid == 0 && row < n) fin[(size_t)row * 3 + 1] = s + bao0;
        }
    }
}

// ---------------- per-graph mean pool ----------------

__global__ void pool_kernel(const float* __restrict__ fin, const int* __restrict__ batch,
                            float* __restrict__ out, int n) {
    int g = blockIdx.x, t = threadIdx.x;
    int lo = 0, hi = n;
    while (lo < hi) { int mid = (lo + hi) >> 1; if (batch[mid] < g) lo = mid + 1; else hi = mid; }
    int start = lo;
    lo = 0; hi = n;
    while (lo < hi) { int mid = (lo + hi) >> 1; if (batch[mid] < g + 1) lo = mid + 1; else hi = mid; }
    int end = lo;
    float s0 = 0.f, s1 = 0.f, s2 = 0.f;
    for (int i = start + t; i < end; i += 256) {
        s0 += fin[(size_t)i * 3 + 0];
        s1 += fin[(size_t)i * 3 + 1];
        s2 += fin[(size_t)i * 3 + 2];
    }
    __shared__ float r0[256], r1[256], r2[256];
    r0[t] = s0; r1[t] = s1; r2[t] = s2;
    __syncthreads();
    for (int off = 128; off > 0; off >>= 1) {
        if (t < off) { r0[t] += r0[t + off]; r1[t] += r1[t + off]; r2[t] += r2[t + off]; }
        __syncthreads();
    }
    if (t == 0) {
        float c = (float)max(end - start, 1);
        out[g * 3 + 0] = r0[0] / c;
        out[g * 3 + 1] = r1[0] / c;
        out[g * 3 + 2] = r2[0] / c;
    }
}

// ---------------- launch ----------------

extern "C" void kernel_launch(void* const* d_in, const int* in_sizes, int n_in,
                              void* d_out, int out_size, void* d_ws, size_t ws_size,
                              hipStream_t stream) {
    const float* x    = (const float*)d_in[0];
    const int*   ei   = (const int*)d_in[1];
    const int*   batch= (const int*)d_in[2];
    const float* Wl0  = (const float*)d_in[3];
    const float* bl0  = (const float*)d_in[4];
    const float* Wr0  = (const float*)d_in[5];
    const float* Wl1  = (const float*)d_in[6];
    const float* bl1  = (const float*)d_in[7];
    const float* Wr1  = (const float*)d_in[8];
    const float* Wl2  = (const float*)d_in[9];
    const float* bl2  = (const float*)d_in[10];
    const float* Wr2  = (const float*)d_in[11];
    const float* Wfc  = (const float*)d_in[12];
    const float* bfc  = (const float*)d_in[13];
    const float* Wa1  = (const float*)d_in[14];
    const float* ba1  = (const float*)d_in[15];
    const float* Wa2  = (const float*)d_in[16];
    const float* ba2  = (const float*)d_in[17];
    const float* Wao  = (const float*)d_in[18];
    const float* bao  = (const float*)d_in[19];

    const int N = in_sizes[0] / 32;
    const int E = in_sizes[1] / 2;
    const int G = out_size / 3;
    const int* src = ei;
    const int* dst = ei + E;
    float* out = (float*)d_out;
    const int NB = (N + NR - 1) / NR;
    const int NBLK = (E + PART_CH - 1) / PART_CH;

    char* p = (char*)d_ws;
    auto carve = [&](size_t bytes) {
        void* r = (void*)p;
        p += (bytes + 255) & ~(size_t)255;
        return r;
    };
    int*           hist_blk = (int*)carve((size_t)NBLK * NB * 4);
    int*           pbase    = (int*)carve((size_t)NBLK * NB * 4);
    int*           btot     = (int*)carve((size_t)NB * 4);
    int*           bstart   = (int*)carve((size_t)(NB + 1) * 4);
    int*           row_start= (int*)carve((size_t)(N + 1) * 4);
    unsigned*      packed   = (unsigned*)carve((size_t)E * 4);
    int*           srcs     = (int*)carve((size_t)E * 4);
    ushortT*       aggbf    = (ushortT*)carve((size_t)N * 128 * 2);
    ushortT*       xbf      = (ushortT*)carve((size_t)N * 32 * 2);
    ushortT*       hbf0     = (ushortT*)carve((size_t)N * 128 * 2);
    ushortT*       hbf1     = (ushortT*)carve((size_t)N * 128 * 2);
    unsigned char* hf8_0    = (unsigned char*)carve((size_t)N * 128);
    unsigned char* hf8_1    = (unsigned char*)carve((size_t)N * 128);
    float*         fin      = (float*)carve((size_t)N * 3 * 4);
    ushortT*       Wt0      = (ushortT*)carve((size_t)128 * 64 * 2);
    ushortT*       Wt1      = (ushortT*)carve((size_t)128 * 256 * 2);
    ushortT*       Wt2      = (ushortT*)carve((size_t)128 * 256 * 2);
    ushortT*       Wa2t     = (ushortT*)carve((size_t)128 * 128 * 2);

    const int gemm_grid = (N + 127) / 128;
    const int n4 = N * 32 / 4;

    // fused input/weight prep
    prep_fused<<<(n4 + 90112 + 255) / 256, 256, 0, stream>>>(
        x, xbf, n4, Wl0, Wr0, Wl1, Wr1, Wl2, Wr2, Wa2, Wt0, Wt1, Wt2, Wa2t);

    // CSR build (radix-style, parallel scans, no global atomics)
    hist_pass<<<NBLK, 256, 0, stream>>>(dst, hist_blk, E, NB);
    col_scan<<<(NB + 255) / 256, 256, 0, stream>>>(hist_blk, pbase, btot, NB, NBLK);
    bstart_scan<<<1, 512, 0, stream>>>(btot, bstart, NB, E);
    partition_edges<<<NBLK, 256, 0, stream>>>(src, dst, pbase, bstart, packed, E, NB);
    bucket_sort<<<NB, 256, 0, stream>>>(packed, bstart, row_start, srcs, N);

    // layer 0 (KH=32): bf16 gather on x; dual-write h0 (bf16 + fp8)
    aggregate_mean_bf16<4><<<(N * 2 + 255) / 256, 256, 0, stream>>>(
        (const uint4*)xbf, aggbf, srcs, row_start, N);
    gemm_mfma<32, true, true><<<gemm_grid, 256, 0, stream>>>(
        aggbf, xbf, Wt0, bl0, (float*)nullptr, hbf0, hf8_0, N);
    // layer 1 (KH=128): fp8 gather on h0; dual-write h1
    aggregate_mean_fp8<<<(N * 8 + 255) / 256, 256, 0, stream>>>(
        (const uint4*)hf8_0, aggbf, srcs, row_start, N);
    gemm_mfma<128, true, true><<<gemm_grid, 256, 0, stream>>>(
        aggbf, hbf0, Wt1, bl1, (float*)nullptr, hbf1, hf8_1, N);
    // layer 2 (KH=128): fp8 gather on h1; fused d1/d3 epilogue -> fin
    aggregate_mean_fp8<<<(N * 8 + 255) / 256, 256, 0, stream>>>(
        (const uint4*)hf8_1, aggbf, srcs, row_start, N);
    gemm_mfma_fin<128><<<gemm_grid, 256, 0, stream>>>(
        aggbf, hbf1, Wt2, bl2, Wfc, bfc, fin, N);

    // head aux MLP (MFMA, register-built A) -> fin[:,1]
    head_mfma<<<gemm_grid, 256, 0, stream>>>(
        Wa2t, Wa1, ba1, ba2, Wao, bao, fin, N);

    // per-graph mean pool
    pool_kernel<<<G, 256, 0, stream>>>(fin, batch, out, N);
}

// Round 11
// 357.222 us; speedup vs baseline: 1.3662x; 1.0535x over previous
//
#include <hip/hip_runtime.h>

#define NR 128        // dst nodes per bucket
#define PART_CH 4096  // edges per partition/count block
typedef unsigned short ushortT;
typedef __attribute__((ext_vector_type(8))) short short8;
typedef __attribute__((ext_vector_type(4))) float float4v;
typedef __attribute__((ext_vector_type(2))) float float2v;

__device__ __forceinline__ unsigned short f32_to_bf16_rne(float f) {
    unsigned u = __float_as_uint(f);
    unsigned r = (u + 0x7fffu + ((u >> 16) & 1u)) >> 16;
    return (unsigned short)r;
}

__device__ __forceinline__ unsigned char f32_to_fp8(float f) {
    return (unsigned char)(__builtin_amdgcn_cvt_pk_fp8_f32(f, f, 0, false) & 0xff);
}

__device__ __forceinline__ void accum8(float* acc, uint4 v) {
    unsigned u[4] = {v.x, v.y, v.z, v.w};
#pragma unroll
    for (int q = 0; q < 4; q++) {
        acc[2 * q]     += __uint_as_float(u[q] << 16);
        acc[2 * q + 1] += __uint_as_float(u[q] & 0xffff0000u);
    }
}

// 16 fp8 values in a uint4 -> acc[16]
__device__ __forceinline__ void accum16_fp8(float* acc, uint4 v) {
    unsigned u[4] = {v.x, v.y, v.z, v.w};
#pragma unroll
    for (int q = 0; q < 4; q++) {
        float2v lo = __builtin_amdgcn_cvt_pk_f32_fp8(u[q], false);
        float2v hi = __builtin_amdgcn_cvt_pk_f32_fp8(u[q], true);
        acc[4 * q + 0] += lo.x;
        acc[4 * q + 1] += lo.y;
        acc[4 * q + 2] += hi.x;
        acc[4 * q + 3] += hi.y;
    }
}

// ---------------- CSR build: bucketed counting sort (R7-measured form + batched loads) --

__launch_bounds__(256)
__global__ void bucket_count(const int* __restrict__ dst, int* __restrict__ bcnt, int E, int NB) {
    __shared__ int h[1024];
    int t = threadIdx.x;
    for (int j = t; j < NB; j += 256) h[j] = 0;
    __syncthreads();
    int e0 = blockIdx.x * PART_CH;
    int e1 = min(e0 + PART_CH, E);
    for (int base = e0; base < e1; base += 2048) {
        int idx = base + t;
        int d[8];
        int cnt = 0;
#pragma unroll
        for (int u = 0; u < 8; u++) {
            int e = idx + u * 256;
            if (e < e1) d[cnt++] = dst[e];
        }
        for (int u = 0; u < cnt; u++) atomicAdd(&h[d[u] >> 7], 1);
    }
    __syncthreads();
    for (int j = t; j < NB; j += 256) {
        int v = h[j];
        if (v) atomicAdd(&bcnt[j], v);
    }
}

__launch_bounds__(256)
__global__ void bucket_scan(const int* __restrict__ bcnt, int* __restrict__ bstart,
                            int* __restrict__ gcur, int NB, int E) {
    __shared__ int sh[256];
    int t = threadIdx.x;
    int v[4];
    int tot = 0;
#pragma unroll
    for (int j = 0; j < 4; j++) {
        int idx = t * 4 + j;
        v[j] = (idx < NB) ? bcnt[idx] : 0;
        tot += v[j];
    }
    sh[t] = tot;
    __syncthreads();
    for (int off = 1; off < 256; off <<= 1) {
        int add = (t >= off) ? sh[t - off] : 0;
        __syncthreads();
        sh[t] += add;
        __syncthreads();
    }
    int run = sh[t] - tot;
#pragma unroll
    for (int j = 0; j < 4; j++) {
        int idx = t * 4 + j;
        if (idx < NB) { bstart[idx] = run; gcur[idx] = run; }
        run += v[j];
    }
    if (t == 0) bstart[NB] = E;
}

// partition edges into buckets; packed record = src | (dst&127)<<17  (src < 2^17)
__launch_bounds__(256)
__global__ void partition_edges(const int* __restrict__ src, const int* __restrict__ dst,
                                int* __restrict__ gcur, unsigned* __restrict__ packed,
                                int E, int NB) {
    __shared__ int hist[1024];
    __shared__ int base[1024];
    int t = threadIdx.x;
    int e0 = blockIdx.x * PART_CH;
    int e1 = min(e0 + PART_CH, E);
    for (int j = t; j < NB; j += 256) hist[j] = 0;
    __syncthreads();
    for (int bb = e0; bb < e1; bb += 2048) {
        int idx = bb + t;
        int d[8];
        int cnt = 0;
#pragma unroll
        for (int u = 0; u < 8; u++) {
            int e = idx + u * 256;
            if (e < e1) d[cnt++] = dst[e];
        }
        for (int u = 0; u < cnt; u++) atomicAdd(&hist[d[u] >> 7], 1);
    }
    __syncthreads();
    for (int j = t; j < NB; j += 256) {
        int h = hist[j];
        base[j] = h ? atomicAdd(&gcur[j], h) : 0;
    }
    __syncthreads();
    for (int j = t; j < NB; j += 256) hist[j] = base[j];
    __syncthreads();
    for (int bb = e0; bb < e1; bb += 2048) {
        int idx = bb + t;
        int d[8], s[8];
        int cnt = 0;
#pragma unroll
        for (int u = 0; u < 8; u++) {
            int e = idx + u * 256;
            if (e < e1) { d[cnt] = dst[e]; s[cnt] = src[e]; cnt++; }
        }
        for (int u = 0; u < cnt; u++) {
            int dd = d[u];
            int pos = atomicAdd(&hist[dd >> 7], 1);
            packed[pos] = (unsigned)s[u] | ((unsigned)(dd & (NR - 1)) << 17);
        }
    }
}

__launch_bounds__(256)
__global__ void bucket_sort(const unsigned* __restrict__ packed, const int* __restrict__ bstart,
                            int* __restrict__ row_start, int* __restrict__ srcs, int N) {
    __shared__ int cnt[NR];
    __shared__ int sc[NR];
    __shared__ int cur[NR];
    int b = blockIdx.x, t = threadIdx.x;
    int nb0 = b * NR;
    int nnode = min(NR, N - nb0);
    int lo = bstart[b], hi = bstart[b + 1];
    if (t < NR) cnt[t] = 0;
    __syncthreads();
    for (int bb = lo; bb < hi; bb += 2048) {
        int idx = bb + t;
        unsigned pk[8];
        int c = 0;
#pragma unroll
        for (int u = 0; u < 8; u++) {
            int e = idx + u * 256;
            if (e < hi) pk[c++] = packed[e];
        }
        for (int u = 0; u < c; u++) atomicAdd(&cnt[pk[u] >> 17], 1);
    }
    __syncthreads();
    if (t < NR) sc[t] = cnt[t];
    __syncthreads();
    for (int off = 1; off < NR; off <<= 1) {
        int add = (t >= off && t < NR) ? sc[t - off] : 0;
        __syncthreads();
        if (t < NR) sc[t] += add;
        __syncthreads();
    }
    if (t < nnode) {
        int s = lo + sc[t] - cnt[t];
        row_start[nb0 + t] = s;
        cur[t] = s;
    }
    if (t == 0 && nb0 + nnode == N) row_start[N] = hi;
    __syncthreads();
    for (int bb = lo; bb < hi; bb += 2048) {
        int idx = bb + t;
        unsigned pk[8];
        int c = 0;
#pragma unroll
        for (int u = 0; u < 8; u++) {
            int e = idx + u * 256;
            if (e < hi) pk[c++] = packed[e];
        }
        for (int u = 0; u < c; u++) {
            int pos = atomicAdd(&cur[pk[u] >> 17], 1);
            srcs[pos] = (int)(pk[u] & 0x1FFFFu);
        }
    }
}

// ---------------- fused prep: x -> bf16 + all weight transposes ----------------
// Wt layout: Wt[col][(k + 8*col) % KT] = bf16(Wcat[k][col])

__global__ void prep_fused(const float* __restrict__ x, ushortT* __restrict__ xbf, int n4,
                           const float* __restrict__ Wl0, const float* __restrict__ Wr0,
                           const float* __restrict__ Wl1, const float* __restrict__ Wr1,
                           const float* __restrict__ Wl2, const float* __restrict__ Wr2,
                           const float* __restrict__ Wa2,
                           ushortT* __restrict__ Wt0, ushortT* __restrict__ Wt1,
                           ushortT* __restrict__ Wt2, ushortT* __restrict__ Wa2t) {
    int tid0 = blockIdx.x * 256 + threadIdx.x;
    if (tid0 < n4) {
        float4 v = ((const float4*)x)[tid0];
        ushort4 o;
        o.x = f32_to_bf16_rne(v.x);
        o.y = f32_to_bf16_rne(v.y);
        o.z = f32_to_bf16_rne(v.z);
        o.w = f32_to_bf16_rne(v.w);
        ((ushort4*)xbf)[tid0] = o;
        return;
    }
    int tid = tid0 - n4;
    if (tid < 8192) {  // Wt0: KH=32, KT=64
        int col = tid >> 6, k = tid & 63;
        float v = (k < 32) ? Wl0[k * 128 + col] : Wr0[(k - 32) * 128 + col];
        Wt0[col * 64 + ((k + 8 * col) & 63)] = f32_to_bf16_rne(v);
    } else if (tid < 8192 + 32768) {  // Wt1: KT=256
        int j = tid - 8192;
        int col = j >> 8, k = j & 255;
        float v = (k < 128) ? Wl1[k * 128 + col] : Wr1[(k - 128) * 128 + col];
        Wt1[col * 256 + ((k + 8 * col) & 255)] = f32_to_bf16_rne(v);
    } else if (tid < 8192 + 65536) {  // Wt2: KT=256
        int j = tid - 8192 - 32768;
        int col = j >> 8, k = j & 255;
        float v = (k < 128) ? Wl2[k * 128 + col] : Wr2[(k - 128) * 128 + col];
        Wt2[col * 256 + ((k + 8 * col) & 255)] = f32_to_bf16_rne(v);
    } else if (tid < 8192 + 65536 + 16384) {  // Wa2t: KT=128
        int j = tid - 8192 - 65536;
        int col = j >> 7, k = j & 127;
        Wa2t[col * 128 + ((k + 8 * col) & 127)] = f32_to_bf16_rne(Wa2[k * 128 + col]);
    }
}

// ---------------- aggregation: bf16 input (layer 0, 32 feats) ----------------

template <int CPN>
__launch_bounds__(256)
__global__ void aggregate_mean_bf16(const uint4* __restrict__ hin, ushortT* __restrict__ out,
                                    const int* __restrict__ srcs, const int* __restrict__ rs, int n) {
    constexpr int TPN = CPN / 2;
    int tid = blockIdx.x * 256 + threadIdx.x;
    if (tid >= n * TPN) return;
    int i = tid / TPN;
    int c = tid & (TPN - 1);
    int lo = rs[i], hi = rs[i + 1];
    float acc0[8], acc1[8];
#pragma unroll
    for (int q = 0; q < 8; q++) { acc0[q] = 0.f; acc1[q] = 0.f; }
    int e = lo;
    for (; e + 8 <= hi; e += 8) {
        int s[8];
#pragma unroll
        for (int u = 0; u < 8; u++) s[u] = srcs[e + u];
        uint4 va[8], vb[8];
#pragma unroll
        for (int u = 0; u < 8; u++) {
            va[u] = hin[(size_t)s[u] * CPN + c];
            vb[u] = hin[(size_t)s[u] * CPN + c + TPN];
        }
#pragma unroll
        for (int u = 0; u < 8; u++) { accum8(acc0, va[u]); accum8(acc1, vb[u]); }
    }
    for (; e < hi; ++e) {
        int s = srcs[e];
        accum8(acc0, hin[(size_t)s * CPN + c]);
        accum8(acc1, hin[(size_t)s * CPN + c + TPN]);
    }
    float inv = 1.0f / (float)max(hi - lo, 1);
    uint4 o0, o1;
    o0.x = (unsigned)f32_to_bf16_rne(acc0[0] * inv) | ((unsigned)f32_to_bf16_rne(acc0[1] * inv) << 16);
    o0.y = (unsigned)f32_to_bf16_rne(acc0[2] * inv) | ((unsigned)f32_to_bf16_rne(acc0[3] * inv) << 16);
    o0.z = (unsigned)f32_to_bf16_rne(acc0[4] * inv) | ((unsigned)f32_to_bf16_rne(acc0[5] * inv) << 16);
    o0.w = (unsigned)f32_to_bf16_rne(acc0[6] * inv) | ((unsigned)f32_to_bf16_rne(acc0[7] * inv) << 16);
    o1.x = (unsigned)f32_to_bf16_rne(acc1[0] * inv) | ((unsigned)f32_to_bf16_rne(acc1[1] * inv) << 16);
    o1.y = (unsigned)f32_to_bf16_rne(acc1[2] * inv) | ((unsigned)f32_to_bf16_rne(acc1[3] * inv) << 16);
    o1.z = (unsigned)f32_to_bf16_rne(acc1[4] * inv) | ((unsigned)f32_to_bf16_rne(acc1[5] * inv) << 16);
    o1.w = (unsigned)f32_to_bf16_rne(acc1[6] * inv) | ((unsigned)f32_to_bf16_rne(acc1[7] * inv) << 16);
    ((uint4*)out)[(size_t)i * CPN + c] = o0;
    ((uint4*)out)[(size_t)i * CPN + c + TPN] = o1;
}

// ---------------- aggregation: fp8 input (layers 1/2, 128 feats) ----------------
// row = 128 fp8 = 8 uint4; 8 threads/node, 1 uint4 (16 feats) each; f32 acc; bf16 out.

__launch_bounds__(256)
__global__ void aggregate_mean_fp8(const uint4* __restrict__ hin, ushortT* __restrict__ out,
                                   const int* __restrict__ srcs, const int* __restrict__ rs, int n) {
    int tid = blockIdx.x * 256 + threadIdx.x;
    if (tid >= n * 8) return;
    int i = tid >> 3;
    int c = tid & 7;
    int lo = rs[i], hi = rs[i + 1];
    float acc[16];
#pragma unroll
    for (int q = 0; q < 16; q++) acc[q] = 0.f;
    int e = lo;
    for (; e + 8 <= hi; e += 8) {
        int s[8];
#pragma unroll
        for (int u = 0; u < 8; u++) s[u] = srcs[e + u];
        uint4 v[8];
#pragma unroll
        for (int u = 0; u < 8; u++) v[u] = hin[(size_t)s[u] * 8 + c];
#pragma unroll
        for (int u = 0; u < 8; u++) accum16_fp8(acc, v[u]);
    }
    for (; e + 4 <= hi; e += 4) {
        int s[4];
#pragma unroll
        for (int u = 0; u < 4; u++) s[u] = srcs[e + u];
        uint4 v[4];
#pragma unroll
        for (int u = 0; u < 4; u++) v[u] = hin[(size_t)s[u] * 8 + c];
#pragma unroll
        for (int u = 0; u < 4; u++) accum16_fp8(acc, v[u]);
    }
    for (; e < hi; ++e) accum16_fp8(acc, hin[(size_t)srcs[e] * 8 + c]);
    float inv = 1.0f / (float)max(hi - lo, 1);
    uint4 o0, o1;
    o0.x = (unsigned)f32_to_bf16_rne(acc[0] * inv)  | ((unsigned)f32_to_bf16_rne(acc[1] * inv) << 16);
    o0.y = (unsigned)f32_to_bf16_rne(acc[2] * inv)  | ((unsigned)f32_to_bf16_rne(acc[3] * inv) << 16);
    o0.z = (unsigned)f32_to_bf16_rne(acc[4] * inv)  | ((unsigned)f32_to_bf16_rne(acc[5] * inv) << 16);
    o0.w = (unsigned)f32_to_bf16_rne(acc[6] * inv)  | ((unsigned)f32_to_bf16_rne(acc[7] * inv) << 16);
    o1.x = (unsigned)f32_to_bf16_rne(acc[8] * inv)  | ((unsigned)f32_to_bf16_rne(acc[9] * inv) << 16);
    o1.y = (unsigned)f32_to_bf16_rne(acc[10] * inv) | ((unsigned)f32_to_bf16_rne(acc[11] * inv) << 16);
    o1.z = (unsigned)f32_to_bf16_rne(acc[12] * inv) | ((unsigned)f32_to_bf16_rne(acc[13] * inv) << 16);
    o1.w = (unsigned)f32_to_bf16_rne(acc[14] * inv) | ((unsigned)f32_to_bf16_rne(acc[15] * inv) << 16);
    ((uint4*)out)[(size_t)i * 16 + c * 2]     = o0;
    ((uint4*)out)[(size_t)i * 16 + c * 2 + 1] = o1;
}

// ---------------- MFMA GEMM: out = relu([Am | Ah] @ [Wl;Wr] + bias) --------------------

template <int KH, bool OUT_BF16, bool OUT_FP8>
__launch_bounds__(256, 2)
__global__ void gemm_mfma(const ushortT* __restrict__ Am, const ushortT* __restrict__ Ah,
                          const ushortT* __restrict__ Wt, const float* __restrict__ bias,
                          float* __restrict__ outf, ushortT* __restrict__ outbf,
                          unsigned char* __restrict__ outf8, int n) {
    constexpr int KT = 2 * KH;
    __shared__ ushortT sW[128 * KT];
    int t = threadIdx.x;
    constexpr int TOT16 = 128 * KT * 2 / 16;
    {
        const uint4* Wg = (const uint4*)Wt;
        uint4* Ws = (uint4*)sW;
        for (int j = t; j < TOT16; j += 256) Ws[j] = Wg[j];
    }
    __syncthreads();
    int wv = t >> 6, lane = t & 63;
    int q = lane >> 4, cid = lane & 15;
    int rbase = blockIdx.x * 128 + wv * 32;
    int r0 = rbase + cid, r1 = r0 + 16;
    int r0c = min(r0, n - 1), r1c = min(r1, n - 1);
    float4v acc[2][8];
#pragma unroll
    for (int i = 0; i < 2; i++)
#pragma unroll
        for (int j = 0; j < 8; j++) acc[i][j] = (float4v){0.f, 0.f, 0.f, 0.f};
    int swz = q * 8 + 8 * cid;
#pragma unroll
    for (int ks = 0; ks < KT / 32; ++ks) {
        int kk = ks * 32;
        const ushortT* abase = (kk < KH) ? Am : Ah;
        int kc = (kk < KH) ? kk : kk - KH;
        short8 a0 = *(const short8*)(abase + (size_t)r0c * KH + kc + q * 8);
        short8 a1 = *(const short8*)(abase + (size_t)r1c * KH + kc + q * 8);
#pragma unroll
        for (int j = 0; j < 8; ++j) {
            int col = j * 16 + cid;
            int p = (kk + swz + j * 128) & (KT - 1);
            short8 b = *(const short8*)(sW + col * KT + p);
            acc[0][j] = __builtin_amdgcn_mfma_f32_16x16x32_bf16(a0, b, acc[0][j], 0, 0, 0);
            acc[1][j] = __builtin_amdgcn_mfma_f32_16x16x32_bf16(a1, b, acc[1][j], 0, 0, 0);
        }
    }
    float bo[8];
#pragma unroll
    for (int j = 0; j < 8; ++j) bo[j] = bias[j * 16 + cid];
#pragma unroll
    for (int i = 0; i < 2; ++i) {
#pragma unroll
        for (int rr = 0; rr < 4; ++rr) {
            int row = rbase + i * 16 + q * 4 + rr;
            if (row < n) {
#pragma unroll
                for (int j = 0; j < 8; ++j) {
                    int col = j * 16 + cid;
                    float v = fmaxf(acc[i][j][rr] + bo[j], 0.f);
                    if (OUT_BF16) outbf[(size_t)row * 128 + col] = f32_to_bf16_rne(v);
                    if (OUT_FP8)  outf8[(size_t)row * 128 + col] = f32_to_fp8(v);
                    if (!OUT_BF16 && !OUT_FP8) outf[(size_t)row * 128 + col] = v;
                }
            }
        }
    }
}

// ---- layer-2 variant: h3 never materialized; epilogue computes d1/d3 -> fin[:,0],fin[:,2]

template <int KH>
__launch_bounds__(256, 2)
__global__ void gemm_mfma_fin(const ushortT* __restrict__ Am, const ushortT* __restrict__ Ah,
                              const ushortT* __restrict__ Wt, const float* __restrict__ bias,
                              const float* __restrict__ Wfc, const float* __restrict__ bfc,
                              float* __restrict__ fin, int n) {
    constexpr int KT = 2 * KH;
    __shared__ ushortT sW[128 * KT];
    int t = threadIdx.x;
    constexpr int TOT16 = 128 * KT * 2 / 16;
    {
        const uint4* Wg = (const uint4*)Wt;
        uint4* Ws = (uint4*)sW;
        for (int j = t; j < TOT16; j += 256) Ws[j] = Wg[j];
    }
    __syncthreads();
    int wv = t >> 6, lane = t & 63;
    int q = lane >> 4, cid = lane & 15;
    int rbase = blockIdx.x * 128 + wv * 32;
    int r0 = rbase + cid, r1 = r0 + 16;
    int r0c = min(r0, n - 1), r1c = min(r1, n - 1);
    float4v acc[2][8];
#pragma unroll
    for (int i = 0; i < 2; i++)
#pragma unroll
        for (int j = 0; j < 8; j++) acc[i][j] = (float4v){0.f, 0.f, 0.f, 0.f};
    int swz = q * 8 + 8 * cid;
#pragma unroll
    for (int ks = 0; ks < KT / 32; ++ks) {
        int kk = ks * 32;
        const ushortT* abase = (kk < KH) ? Am : Ah;
        int kc = (kk < KH) ? kk : kk - KH;
        short8 a0 = *(const short8*)(abase + (size_t)r0c * KH + kc + q * 8);
        short8 a1 = *(const short8*)(abase + (size_t)r1c * KH + kc + q * 8);
#pragma unroll
        for (int j = 0; j < 8; ++j) {
            int col = j * 16 + cid;
            int p = (kk + swz + j * 128) & (KT - 1);
            short8 b = *(const short8*)(sW + col * KT + p);
            acc[0][j] = __builtin_amdgcn_mfma_f32_16x16x32_bf16(a0, b, acc[0][j], 0, 0, 0);
            acc[1][j] = __builtin_amdgcn_mfma_f32_16x16x32_bf16(a1, b, acc[1][j], 0, 0, 0);
        }
    }
    float bo[8], w1[8], w3[8];
#pragma unroll
    for (int j = 0; j < 8; ++j) {
        int col = j * 16 + cid;
        bo[j] = bias[col];
        w1[j] = Wfc[col * 3 + 0];
        w3[j] = Wfc[col * 3 + 2];
    }
    float bfc0 = bfc[0], bfc2 = bfc[2];
#pragma unroll
    for (int i = 0; i < 2; ++i) {
#pragma unroll
        for (int rr = 0; rr < 4; ++rr) {
            float p1 = 0.f, p3 = 0.f;
#pragma unroll
            for (int j = 0; j < 8; ++j) {
                float v = fmaxf(acc[i][j][rr] + bo[j], 0.f);
                p1 += v * w1[j];
                p3 += v * w3[j];
            }
            p1 += __shfl_xor(p1, 1, 64); p3 += __shfl_xor(p3, 1, 64);
            p1 += __shfl_xor(p1, 2, 64); p3 += __shfl_xor(p3, 2, 64);
            p1 += __shfl_xor(p1, 4, 64); p3 += __shfl_xor(p3, 4, 64);
            p1 += __shfl_xor(p1, 8, 64); p3 += __shfl_xor(p3, 8, 64);
            int row = rbase + i * 16 + q * 4 + rr;
            if (cid == 0 && row < n) {
                fin[(size_t)row * 3 + 0] = p1 + bfc0;
                fin[(size_t)row * 3 + 2] = p3 + bfc2;
            }
        }
    }
}

// ---------------- head: a1 built in registers + a2 MFMA + Wao reduce -> fin[:,1] -------

__launch_bounds__(256, 4)
__global__ void head_mfma(const ushortT* __restrict__ Wa2t, const float* __restrict__ Wa1,
                          const float* __restrict__ ba1, const float* __restrict__ ba2,
                          const float* __restrict__ Wao, const float* __restrict__ bao,
                          float* __restrict__ fin, int n) {
    __shared__ ushortT sW[128 * 128];   // 32 KB
    __shared__ float sD1[128], sD3[128];
    __shared__ float sWa1a[128], sWa1b[128], sBa1[128];
    int t = threadIdx.x;
    {
        const uint4* Wg = (const uint4*)Wa2t;
        uint4* Ws = (uint4*)sW;
        for (int j = t; j < 2048; j += 256) Ws[j] = Wg[j];
    }
    int rbase = blockIdx.x * 128;
    if (t < 128) {
        sWa1a[t] = Wa1[t];
        sWa1b[t] = Wa1[128 + t];
        sBa1[t] = ba1[t];
        int row = min(rbase + t, n - 1);
        sD1[t] = fin[(size_t)row * 3 + 0];
        sD3[t] = fin[(size_t)row * 3 + 2];
    }
    __syncthreads();
    int wv = t >> 6, lane = t & 63;
    int q = lane >> 4, cid = lane & 15;
    int rl0 = wv * 32 + cid, rl1 = rl0 + 16;
    float d1a = sD1[rl0], d3a = sD3[rl0];
    float d1b = sD1[rl1], d3b = sD3[rl1];
    float4v acc[2][8];
#pragma unroll
    for (int i = 0; i < 2; i++)
#pragma unroll
        for (int j = 0; j < 8; j++) acc[i][j] = (float4v){0.f, 0.f, 0.f, 0.f};
    int swz = q * 8 + 8 * cid;
#pragma unroll
    for (int ks = 0; ks < 4; ++ks) {
        int k0 = ks * 32 + q * 8;
        short8 a0, a1;
#pragma unroll
        for (int j = 0; j < 8; ++j) {
            int k = k0 + j;
            float w0 = sWa1a[k], w1 = sWa1b[k], bb = sBa1[k];
            float v0 = fmaxf(fmaf(d1a, w0, fmaf(d3a, w1, bb)), 0.f);
            float v1 = fmaxf(fmaf(d1b, w0, fmaf(d3b, w1, bb)), 0.f);
            a0[j] = (short)f32_to_bf16_rne(v0);
            a1[j] = (short)f32_to_bf16_rne(v1);
        }
        int p = (ks * 32 + swz) & 127;
#pragma unroll
        for (int j = 0; j < 8; ++j) {
            short8 b = *(const short8*)(sW + (j * 16 + cid) * 128 + p);
            acc[0][j] = __builtin_amdgcn_mfma_f32_16x16x32_bf16(a0, b, acc[0][j], 0, 0, 0);
            acc[1][j] = __builtin_amdgcn_mfma_f32_16x16x32_bf16(a1, b, acc[1][j], 0, 0, 0);
        }
    }
    float b2[8], wo[8];
#pragma unroll
    for (int j = 0; j < 8; ++j) {
        int col = j * 16 + cid;
        b2[j] = ba2[col];
        wo[j] = Wao[col];
    }
    float bao0 = bao[0];
#pragma unroll
    for (int i = 0; i < 2; ++i) {
#pragma unroll
        for (int rr = 0; rr < 4; ++rr) {
            float s = 0.f;
#pragma unroll
            for (int j = 0; j < 8; ++j) s += fmaxf(acc[i][j][rr] + b2[j], 0.f) * wo[j];
            s += __shfl_xor(s, 1, 64);
            s += __shfl_xor(s, 2, 64);
            s += __shfl_xor(s, 4, 64);
            s += __shfl_xor(s, 8, 64);
            int row = rbase + wv * 32 + i * 16 + q * 4 + rr;
            if (cid == 0 && row < n) fin[(size_t)row * 3 + 1] = s + bao0;
        }
    }
}

// ---------------- per-graph mean pool ----------------

__global__ void pool_kernel(const float* __restrict__ fin, const int* __restrict__ batch,
                            float* __restrict__ out, int n) {
    int g = blockIdx.x, t = threadIdx.x;
    int lo = 0, hi = n;
    while (lo < hi) { int mid = (lo + hi) >> 1; if (batch[mid] < g) lo = mid + 1; else hi = mid; }
    int start = lo;
    lo = 0; hi = n;
    while (lo < hi) { int mid = (lo + hi) >> 1; if (batch[mid] < g + 1) lo = mid + 1; else hi = mid; }
    int end = lo;
    float s0 = 0.f, s1 = 0.f, s2 = 0.f;
    for (int i = start + t; i < end; i += 256) {
        s0 += fin[(size_t)i * 3 + 0];
        s1 += fin[(size_t)i * 3 + 1];
        s2 += fin[(size_t)i * 3 + 2];
    }
    __shared__ float r0[256], r1[256], r2[256];
    r0[t] = s0; r1[t] = s1; r2[t] = s2;
    __syncthreads();
    for (int off = 128; off > 0; off >>= 1) {
        if (t < off) { r0[t] += r0[t + off]; r1[t] += r1[t + off]; r2[t] += r2[t + off]; }
        __syncthreads();
    }
    if (t == 0) {
        float c = (float)max(end - start, 1);
        out[g * 3 + 0] = r0[0] / c;
        out[g * 3 + 1] = r1[0] / c;
        out[g * 3 + 2] = r2[0] / c;
    }
}

// ---------------- launch ----------------

extern "C" void kernel_launch(void* const* d_in, const int* in_sizes, int n_in,
                              void* d_out, int out_size, void* d_ws, size_t ws_size,
                              hipStream_t stream) {
    const float* x    = (const float*)d_in[0];
    const int*   ei   = (const int*)d_in[1];
    const int*   batch= (const int*)d_in[2];
    const float* Wl0  = (const float*)d_in[3];
    const float* bl0  = (const float*)d_in[4];
    const float* Wr0  = (const float*)d_in[5];
    const float* Wl1  = (const float*)d_in[6];
    const float* bl1  = (const float*)d_in[7];
    const float* Wr1  = (const float*)d_in[8];
    const float* Wl2  = (const float*)d_in[9];
    const float* bl2  = (const float*)d_in[10];
    const float* Wr2  = (const float*)d_in[11];
    const float* Wfc  = (const float*)d_in[12];
    const float* bfc  = (const float*)d_in[13];
    const float* Wa1  = (const float*)d_in[14];
    const float* ba1  = (const float*)d_in[15];
    const float* Wa2  = (const float*)d_in[16];
    const float* ba2  = (const float*)d_in[17];
    const float* Wao  = (const float*)d_in[18];
    const float* bao  = (const float*)d_in[19];

    const int N = in_sizes[0] / 32;
    const int E = in_sizes[1] / 2;
    const int G = out_size / 3;
    const int* src = ei;
    const int* dst = ei + E;
    float* out = (float*)d_out;
    const int NB = (N + NR - 1) / NR;

    char* p = (char*)d_ws;
    auto carve = [&](size_t bytes) {
        void* r = (void*)p;
        p += (bytes + 255) & ~(size_t)255;
        return r;
    };
    int*           bcnt     = (int*)carve((size_t)NB * 4);
    int*           bstart   = (int*)carve((size_t)(NB + 1) * 4);
    int*           gcur     = (int*)carve((size_t)NB * 4);
    int*           row_start= (int*)carve((size_t)(N + 1) * 4);
    unsigned*      packed   = (unsigned*)carve((size_t)E * 4);
    int*           srcs     = (int*)carve((size_t)E * 4);
    ushortT*       aggbf    = (ushortT*)carve((size_t)N * 128 * 2);
    ushortT*       xbf      = (ushortT*)carve((size_t)N * 32 * 2);
    ushortT*       hbf0     = (ushortT*)carve((size_t)N * 128 * 2);
    ushortT*       hbf1     = (ushortT*)carve((size_t)N * 128 * 2);
    unsigned char* hf8_0    = (unsigned char*)carve((size_t)N * 128);
    unsigned char* hf8_1    = (unsigned char*)carve((size_t)N * 128);
    float*         fin      = (float*)carve((size_t)N * 3 * 4);
    ushortT*       Wt0      = (ushortT*)carve((size_t)128 * 64 * 2);
    ushortT*       Wt1      = (ushortT*)carve((size_t)128 * 256 * 2);
    ushortT*       Wt2      = (ushortT*)carve((size_t)128 * 256 * 2);
    ushortT*       Wa2t     = (ushortT*)carve((size_t)128 * 128 * 2);

    const int gemm_grid = (N + 127) / 128;
    const int part_grid = (E + PART_CH - 1) / PART_CH;
    const int n4 = N * 32 / 4;

    // fused input/weight prep
    prep_fused<<<(n4 + 90112 + 255) / 256, 256, 0, stream>>>(
        x, xbf, n4, Wl0, Wr0, Wl1, Wr1, Wl2, Wr2, Wa2, Wt0, Wt1, Wt2, Wa2t);

    // CSR build (R7-measured bucketed counting sort, batched loads)
    hipMemsetAsync(bcnt, 0, (size_t)NB * 4, stream);
    bucket_count<<<part_grid, 256, 0, stream>>>(dst, bcnt, E, NB);
    bucket_scan<<<1, 256, 0, stream>>>(bcnt, bstart, gcur, NB, E);
    partition_edges<<<part_grid, 256, 0, stream>>>(src, dst, gcur, packed, E, NB);
    bucket_sort<<<NB, 256, 0, stream>>>(packed, bstart, row_start, srcs, N);

    // layer 0 (KH=32): bf16 gather on x; dual-write h0 (bf16 + fp8)
    aggregate_mean_bf16<4><<<(N * 2 + 255) / 256, 256, 0, stream>>>(
        (const uint4*)xbf, aggbf, srcs, row_start, N);
    gemm_mfma<32, true, true><<<gemm_grid, 256, 0, stream>>>(
        aggbf, xbf, Wt0, bl0, (float*)nullptr, hbf0, hf8_0, N);
    // layer 1 (KH=128): fp8 gather on h0; dual-write h1
    aggregate_mean_fp8<<<(N * 8 + 255) / 256, 256, 0, stream>>>(
        (const uint4*)hf8_0, aggbf, srcs, row_start, N);
    gemm_mfma<128, true, true><<<gemm_grid, 256, 0, stream>>>(
        aggbf, hbf0, Wt1, bl1, (float*)nullptr, hbf1, hf8_1, N);
    // layer 2 (KH=128): fp8 gather on h1; fused d1/d3 epilogue -> fin
    aggregate_mean_fp8<<<(N * 8 + 255) / 256, 256, 0, stream>>>(
        (const uint4*)hf8_1, aggbf, srcs, row_start, N);
    gemm_mfma_fin<128><<<gemm_grid, 256, 0, stream>>>(
        aggbf, hbf1, Wt2, bl2, Wfc, bfc, fin, N);

    // head aux MLP (MFMA, register-built A) -> fin[:,1]
    head_mfma<<<gemm_grid, 256, 0, stream>>>(
        Wa2t, Wa1, ba1, ba2, Wao, bao, fin, N);

    // per-graph mean pool
    pool_kernel<<<G, 256, 0, stream>>>(fin, batch, out, N);
}